// Round 2
// baseline (401.808 us; speedup 1.0000x reference)
//
#include <hip/hip_runtime.h>
#include <hip/hip_bf16.h>
#include <cstdint>
#include <cstddef>

typedef __bf16 bf16;
typedef __bf16 bf16x8 __attribute__((ext_vector_type(8)));
typedef float f32x4 __attribute__((ext_vector_type(4)));

#define MFMA16(a, b, c) __builtin_amdgcn_mfma_f32_16x16x32_bf16(a, b, c, 0, 0, 0)

#define GLOBAL_LOAD_LDS16(gptr, lptr)                                          \
  __builtin_amdgcn_global_load_lds(                                            \
      (const __attribute__((address_space(1))) void*)(gptr),                   \
      (__attribute__((address_space(3))) void*)(lptr), 16, 0, 0)

// ---------------------------------------------------------------------------
// prep: blocks 0..16383 = weight transpose+convert; 16384..20479 = LayerNorm.
// ---------------------------------------------------------------------------
__global__ __launch_bounds__(256) void prep(const float* __restrict__ w_in,
                                            const float* __restrict__ w_attn,
                                            const float* __restrict__ w_ff,
                                            bf16* __restrict__ wt_in,
                                            bf16* __restrict__ wtcat,
                                            const float* __restrict__ x,
                                            const float* __restrict__ ln_w,
                                            const float* __restrict__ ln_b,
                                            bf16* __restrict__ xn) {
  __shared__ __align__(16) char sm[4352];
  if (blockIdx.x < 16384) {
    float(*t)[33] = (float(*)[33])sm;
    int id = blockIdx.x;
    const float* src; bf16* dst;
    int srcN, srccol0, LDO, mode, obase, goff, kcol0, ntn;
    if (id < 3072) {
      src = w_in; dst = wt_in; srcN = 11264; srccol0 = 0; LDO = 1024;
      mode = 0; obase = 0; goff = 0; kcol0 = 0; ntn = 96;
    } else if (id < 7168) {
      id -= 3072; src = w_in; dst = wt_in; srcN = 11264; srccol0 = 3072;
      LDO = 1024; mode = 1; obase = 3072; goff = 0; kcol0 = 0; ntn = 128;
    } else if (id < 11264) {
      id -= 7168; src = w_in; dst = wt_in; srcN = 11264; srccol0 = 7168;
      LDO = 1024; mode = 1; obase = 3072; goff = 64; kcol0 = 0; ntn = 128;
    } else if (id < 12288) {
      id -= 11264; src = w_attn; dst = wtcat; srcN = 1024; srccol0 = 0;
      LDO = 5120; mode = 0; obase = 0; goff = 0; kcol0 = 0; ntn = 32;
    } else {
      id -= 12288; src = w_ff; dst = wtcat; srcN = 1024; srccol0 = 0;
      LDO = 5120; mode = 0; obase = 0; goff = 0; kcol0 = 1024; ntn = 32;
    }
    const int n0 = (id % ntn) * 32, k0 = (id / ntn) * 32;
    const int tx = threadIdx.x & 31, ty = threadIdx.x >> 5;
    for (int i = ty; i < 32; i += 8)
      t[i][tx] = src[(size_t)(k0 + i) * srcN + srccol0 + n0 + tx];
    __syncthreads();
    for (int i = ty; i < 32; i += 8) {
      int n = n0 + i;
      int orow = mode ? (obase + ((n >> 6) << 7) + goff + (n & 63)) : (obase + n);
      dst[(size_t)orow * LDO + kcol0 + k0 + tx] = (bf16)t[tx][i];
    }
  } else {
    float* rs = (float*)sm;          // [256]
    float* rss = rs + 256;           // [256]
    const int row = blockIdx.x - 16384;
    const int tid = threadIdx.x;
    const float* xr = x + (size_t)row * 1024;
    float4 v = *(const float4*)&xr[tid * 4];
    float s = v.x + v.y + v.z + v.w;
    float ss = v.x * v.x + v.y * v.y + v.z * v.z + v.w * v.w;
    rs[tid] = s; rss[tid] = ss;
    __syncthreads();
    for (int off = 128; off > 0; off >>= 1) {
      if (tid < off) { rs[tid] += rs[tid + off]; rss[tid] += rss[tid + off]; }
      __syncthreads();
    }
    const float mean = rs[0] * (1.f / 1024.f);
    const float var = rss[0] * (1.f / 1024.f) - mean * mean;
    const float rstd = rsqrtf(var + 1e-5f);
    const float* vp = (const float*)&v;
    for (int i = 0; i < 4; i++) {
      int c = tid * 4 + i;
      xn[(size_t)row * 1024 + c] = (bf16)((vp[i] - mean) * rstd * ln_w[c] + ln_b[c]);
    }
  }
}

// ---------------------------------------------------------------------------
// V transpose: vt[b][h][d][s] = proj[b*2048+s][2048 + h*64 + d], LDP=3072
// ---------------------------------------------------------------------------
__global__ __launch_bounds__(256) void vtrans(const bf16* __restrict__ proj,
                                              bf16* __restrict__ vt) {
  __shared__ bf16 t[64][80];
  const int tid = threadIdx.x;
  const int s0 = blockIdx.x * 64;
  const int h = blockIdx.y, b = blockIdx.z;
  constexpr size_t LDP = 3072;
  const bf16* src = proj + (size_t)b * 2048 * LDP + 2048 + h * 64;
  {
    int s = tid >> 2, d0 = (tid & 3) * 16;
    *(bf16x8*)&t[s][d0]     = *(const bf16x8*)&src[(size_t)(s0 + s) * LDP + d0];
    *(bf16x8*)&t[s][d0 + 8] = *(const bf16x8*)&src[(size_t)(s0 + s) * LDP + d0 + 8];
  }
  __syncthreads();
  {
    int d = tid >> 2, sb = (tid & 3) * 16;
    bf16* dst = vt + ((size_t)(b * 16 + h) * 64 + d) * 2048 + s0 + sb;
    bf16x8 o0, o1;
    for (int i = 0; i < 8; i++) { o0[i] = t[sb + i][d]; o1[i] = t[sb + 8 + i][d]; }
    *(bf16x8*)&dst[0] = o0;
    *(bf16x8*)&dst[8] = o1;
  }
}

// ---------------------------------------------------------------------------
// Flash attention (fixed-max softmax), 128-key tiles, global_load_lds +
// XOR-swizzled LDS. Row-sum kept as per-lane partials; ONE cross-lane
// reduce at kernel end (softmax l is linear under fixed max).
// ---------------------------------------------------------------------------
__global__ __launch_bounds__(256) void flash_attn(const bf16* __restrict__ proj,
                                                  const bf16* __restrict__ vt,
                                                  bf16* __restrict__ hcat) {
  __shared__ __align__(16) char smem[50176];
  bf16* Ks = (bf16*)smem;                  // [128][64] swizzled
  bf16* Vs = (bf16*)(smem + 16384);        // [64][128] swizzled
  bf16* Ps = (bf16*)(smem + 32768);        // [4][16][136]
  const int tid = threadIdx.x;
  const int wave = tid >> 6, lane = tid & 63;
  const int quad = lane >> 4, l16 = lane & 15;
  const int q0 = blockIdx.x * 64;
  const int h = blockIdx.y, b = blockIdx.z;
  constexpr size_t LDP = 3072;
  const bf16* Qb = proj + (size_t)b * 2048 * LDP + h * 64;
  const bf16* Kb = proj + (size_t)b * 2048 * LDP + 1024 + h * 64;
  const bf16* Vt = vt + (size_t)(b * 16 + h) * 64 * 2048;

  const int qrow = q0 + wave * 16 + l16;
  bf16x8 aq0r = *(const bf16x8*)&Qb[(size_t)qrow * LDP + quad * 8];
  bf16x8 aq1r = *(const bf16x8*)&Qb[(size_t)qrow * LDP + 32 + quad * 8];
  bf16x8 aq0, aq1;
#pragma unroll
  for (int i = 0; i < 8; i++) {
    aq0[i] = (bf16)((float)aq0r[i] * 0.125f);
    aq1[i] = (bf16)((float)aq1r[i] * 0.125f);
  }

  f32x4 O[4] = {};
  float plrow[4] = {0.f, 0.f, 0.f, 0.f};  // per-lane partial row-sums

  const int krow_ = wave * 8 + (lane >> 3);
  const int kq_ = ((lane & 7) ^ (krow_ & 7)) * 8;
  const int vrow_ = wave * 4 + (lane >> 4);
  const int vq_ = ((lane & 15) ^ (vrow_ & 15)) * 8;

  for (int j0 = 0; j0 < 2048; j0 += 128) {
#pragma unroll
    for (int p = 0; p < 4; p++) {
      int kr = p * 32 + krow_;
      GLOBAL_LOAD_LDS16(&Kb[(size_t)(j0 + kr) * LDP + kq_],
                        &Ks[kr * 64 + (lane & 7) * 8]);
      int vr = p * 16 + vrow_;
      GLOBAL_LOAD_LDS16(&Vt[(size_t)vr * 2048 + j0 + vq_],
                        &Vs[vr * 128 + (lane & 15) * 8]);
    }
    __syncthreads();

    f32x4 sa[8];
#pragma unroll
    for (int nt = 0; nt < 8; nt++) {
      int r = nt * 16 + l16;
      bf16x8 bk0 = *(const bf16x8*)&Ks[r * 64 + (quad ^ (r & 7)) * 8];
      bf16x8 bk1 = *(const bf16x8*)&Ks[r * 64 + ((quad + 4) ^ (r & 7)) * 8];
      f32x4 t = {};
      t = MFMA16(aq0, bk0, t);
      sa[nt] = MFMA16(aq1, bk1, t);
    }

    bf16* Pw = Ps + wave * (16 * 136);
#pragma unroll
    for (int r = 0; r < 4; r++) {
      bf16* pr = &Pw[(quad * 4 + r) * 136];
      float ts = 0.f;
#pragma unroll
      for (int nt = 0; nt < 8; nt++) {
        float p = __expf(sa[nt][r]);
        pr[nt * 16 + l16] = (bf16)p;
        ts += p;
      }
      plrow[r] += ts;  // defer cross-lane reduce to epilogue
    }

#pragma unroll
    for (int kg = 0; kg < 4; kg++) {
      bf16x8 aP = *(const bf16x8*)&Pw[l16 * 136 + kg * 32 + quad * 8];
#pragma unroll
      for (int nb = 0; nb < 4; nb++) {
        int vrr = nb * 16 + l16;
        int vsl = ((kg * 4 + quad) ^ (vrr & 15)) * 8;
        bf16x8 bv = *(const bf16x8*)&Vs[vrr * 128 + vsl];
        O[nb] = MFMA16(aP, bv, O[nb]);
      }
    }
    __syncthreads();
  }

#pragma unroll
  for (int r = 0; r < 4; r++) {
    float ts = plrow[r];
#pragma unroll
    for (int d = 1; d < 16; d <<= 1) ts += __shfl_xor(ts, d, 64);
    float inv = 1.f / ts;
    size_t row = (size_t)b * 2048 + q0 + wave * 16 + quad * 4 + r;
#pragma unroll
    for (int nb = 0; nb < 4; nb++)
      hcat[row * 5120 + h * 64 + nb * 16 + l16] = (bf16)(O[nb][r] * inv);
  }
}

// ---------------------------------------------------------------------------
// proj GEMM, v3: 256x256 tile, BK=32, triple-buffered LDS (96 KB), 8-phase
// style fine interleave (T3): each K-tile = 2 phases of {ds_read subtile;
// issue global_load_lds; s_barrier; lgkmcnt(0); setprio(1); 16 MFMA;
// setprio(0); s_barrier}, counted vmcnt(4) once per K-tile (T4), never 0
// in steady state. B-frags read once per K-tile, held across both phases.
// Stage kt+2 into buf (kt+2)%3 while computing kt: vmcnt(4) at tile end
// drains exactly kt+1's 4 loads, leaves kt+2's 4 in flight.
// tiles x<12: plain -> proj[4096][3072]; x>=12: ff|gate gelu -> hcat.
// ---------------------------------------------------------------------------
__global__ __launch_bounds__(512, 2) void gemm_proj(const bf16* __restrict__ A,
                                                    const bf16* __restrict__ Bt,
                                                    bf16* __restrict__ proj,
                                                    bf16* __restrict__ hcat) {
  constexpr int K = 1024, NKT = 32;
  __shared__ __align__(16) char smem[98304];   // 3 x (As 16K + Bs 16K)
  const int tid = threadIdx.x;
  const int wave = tid >> 6, lane = tid & 63;
  const int quad = lane >> 4, l16 = lane & 15;
  const int wm0 = (wave >> 2) * 128, wn0 = (wave & 3) * 64;
  const size_t rowA0 = (size_t)blockIdx.y * 256;
  const size_t rowB0 = (size_t)blockIdx.x * 256;
  const bf16* Ag = A + rowA0 * K;
  const bf16* Bg = Bt + rowB0 * K;

  // staging: thread -> (row = p*128 + tid>>2, slot = tid&3); LDS dest is
  // lane-linear; global k pre-swizzled to match read swizzle.
  const int srow = tid >> 2;
  const int sslot = tid & 3;
  const int rslot = (quad ^ ((l16 >> 1) & 3)) * 8;

  f32x4 acc[8][4] = {};

  auto STAGE_A = [&](int kt, int buf) {
    bf16* As = (bf16*)(smem + buf * 32768);
    const int k0 = kt * 32;
#pragma unroll
    for (int p = 0; p < 2; p++) {
      int r = p * 128 + srow;
      int kq = (sslot ^ ((r >> 1) & 3)) * 8;
      GLOBAL_LOAD_LDS16(&Ag[(size_t)r * K + k0 + kq], &As[r * 32 + sslot * 8]);
    }
  };
  auto STAGE_B = [&](int kt, int buf) {
    bf16* Bs = (bf16*)(smem + buf * 32768) + 256 * 32;
    const int k0 = kt * 32;
#pragma unroll
    for (int p = 0; p < 2; p++) {
      int r = p * 128 + srow;
      int kq = (sslot ^ ((r >> 1) & 3)) * 8;
      GLOBAL_LOAD_LDS16(&Bg[(size_t)r * K + k0 + kq], &Bs[r * 32 + sslot * 8]);
    }
  };

  STAGE_A(0, 0); STAGE_B(0, 0);
  STAGE_A(1, 1); STAGE_B(1, 1);
  asm volatile("s_waitcnt vmcnt(4)" ::: "memory");  // kt0 landed, kt1 in flight
  __builtin_amdgcn_s_barrier();
  asm volatile("" ::: "memory");

  int cbuf = 0, sbuf = 2;
#pragma unroll 1
  for (int kt = 0; kt < NKT; kt++) {
    const bf16* As = (const bf16*)(smem + cbuf * 32768);
    const bf16* Bs = As + 256 * 32;
    const bool st = (kt + 2 < NKT);

    // ---- phase 0: B-frags + A-frags (mh=0), stage A(kt+2) ----
    bf16x8 bfr[4], af[4];
#pragma unroll
    for (int j = 0; j < 4; j++)
      bfr[j] = *(const bf16x8*)&Bs[(wn0 + j * 16 + l16) * 32 + rslot];
#pragma unroll
    for (int i = 0; i < 4; i++)
      af[i] = *(const bf16x8*)&As[(wm0 + i * 16 + l16) * 32 + rslot];
    if (st) STAGE_A(kt + 2, sbuf);
    __builtin_amdgcn_s_barrier();
    asm volatile("s_waitcnt lgkmcnt(0)" ::: "memory");
    __builtin_amdgcn_s_setprio(1);
#pragma unroll
    for (int i = 0; i < 4; i++)
#pragma unroll
      for (int j = 0; j < 4; j++)
        acc[i][j] = MFMA16(af[i], bfr[j], acc[i][j]);
    __builtin_amdgcn_s_setprio(0);
    __builtin_amdgcn_s_barrier();

    // ---- phase 1: A-frags (mh=1), stage B(kt+2), vmcnt at tile end ----
#pragma unroll
    for (int i = 0; i < 4; i++)
      af[i] = *(const bf16x8*)&As[(wm0 + 64 + i * 16 + l16) * 32 + rslot];
    if (st) STAGE_B(kt + 2, sbuf);
    __builtin_amdgcn_s_barrier();
    asm volatile("s_waitcnt lgkmcnt(0)" ::: "memory");
    __builtin_amdgcn_s_setprio(1);
#pragma unroll
    for (int i = 0; i < 4; i++)
#pragma unroll
      for (int j = 0; j < 4; j++)
        acc[4 + i][j] = MFMA16(af[i], bfr[j], acc[4 + i][j]);
    __builtin_amdgcn_s_setprio(0);
    if (kt < NKT - 2) {
      asm volatile("s_waitcnt vmcnt(4)" ::: "memory");  // kt+1 landed
    } else {
      asm volatile("s_waitcnt vmcnt(0)" ::: "memory");  // tail drain
    }
    __builtin_amdgcn_s_barrier();
    asm volatile("" ::: "memory");
    cbuf = (cbuf == 2) ? 0 : cbuf + 1;
    sbuf = (sbuf == 2) ? 0 : sbuf + 1;
  }

  // epilogue: two 128-row halves through LDS, bf16x8 global stores
  {
    const int T2 = (int)blockIdx.x - 12;
    bf16* Cs = (bf16*)smem;          // [128][264]
    constexpr int LDC2 = 264;
#pragma unroll 1
    for (int h = 0; h < 2; h++) {
      if ((wave >> 2) == h) {
#pragma unroll
        for (int i = 0; i < 8; i++)
#pragma unroll
          for (int j = 0; j < 4; j++)
#pragma unroll
            for (int r = 0; r < 4; r++)
              Cs[(i * 16 + quad * 4 + r) * LDC2 + wn0 + j * 16 + l16] =
                  (bf16)acc[i][j][r];
      }
      __syncthreads();
      if (T2 < 0) {
#pragma unroll
        for (int it = 0; it < 8; it++) {
          int idx = it * 512 + tid;          // 128 rows x 32 chunks
          int row = idx >> 5, ch = (idx & 31) * 8;
          *(bf16x8*)&proj[(rowA0 + h * 128 + row) * 3072 + rowB0 + ch] =
              *(const bf16x8*)&Cs[row * LDC2 + ch];
        }
      } else {
#pragma unroll
        for (int it = 0; it < 4; it++) {
          int idx = it * 512 + tid;          // 128 rows x 2 pairs x 8 chunks
          int row = idx >> 4;
          int p = (idx >> 3) & 1, c8 = (idx & 7) * 8;
          bf16x8 f = *(const bf16x8*)&Cs[row * LDC2 + p * 128 + c8];
          bf16x8 g = *(const bf16x8*)&Cs[row * LDC2 + p * 128 + 64 + c8];
          bf16x8 o;
#pragma unroll
          for (int i = 0; i < 8; i++) {
            float xg = (float)g[i];
            float u = 0.7978845608f * (xg + 0.044715f * xg * xg * xg);
            float gl = xg / (1.f + __expf(-2.f * u));
            o[i] = (bf16)((float)f[i] * gl);
          }
          *(bf16x8*)&hcat[(rowA0 + h * 128 + row) * 5120 + 1024 +
                          (2 * T2 + p) * 64 + c8] = o;
        }
      }
      __syncthreads();
    }
  }
}

// ---------------------------------------------------------------------------
// Output GEMM (R8-proven): split-K=4, BK=64, swizzled LDS, bf16 partials.
// ---------------------------------------------------------------------------
__global__ __launch_bounds__(256) void gemm_out(const bf16* __restrict__ A,
                                                const bf16* __restrict__ Bt,
                                                bf16* __restrict__ part) {
  constexpr int LDAB = 5120, LDC = 136;
  __shared__ __align__(16) char smem[32768];
  bf16* As = (bf16*)smem;
  bf16* Bs = As + 128 * 64;
  bf16* Cs = (bf16*)smem;
  const int tid = threadIdx.x;
  const int wave = tid >> 6, lane = tid & 63;
  const int quad = lane >> 4, l16 = lane & 15;
  constexpr int NM = 4, NN = 4;
  const int wm0 = (wave >> 1) * 64, wn0 = (wave & 1) * 64;
  const size_t rowA0 = (size_t)blockIdx.y * 128;
  const size_t rowB0 = (size_t)blockIdx.x * 128;
  const int kbeg = blockIdx.z * 1280, kend = kbeg + 1280;

  const int srow = tid >> 3;
  const int sq = ((tid & 7) ^ (srow & 7)) * 8;
  const int sslot = (tid & 7) * 8;

  f32x4 acc[NM][NN] = {};

  for (int k0 = kbeg; k0 < kend; k0 += 64) {
#pragma unroll
    for (int p = 0; p < 4; p++) {
      int r = p * 32 + srow;
      GLOBAL_LOAD_LDS16(&A[(rowA0 + r) * LDAB + k0 + sq], &As[r * 64 + sslot]);
      GLOBAL_LOAD_LDS16(&Bt[(rowB0 + r) * LDAB + k0 + sq], &Bs[r * 64 + sslot]);
    }
    __syncthreads();
#pragma unroll
    for (int c = 0; c < 2; c++) {
      bf16x8 af[NM], bfr[NN];
#pragma unroll
      for (int i = 0; i < NM; i++) {
        int r = wm0 + i * 16 + l16;
        af[i] = *(const bf16x8*)&As[r * 64 + ((c * 4 + quad) ^ (r & 7)) * 8];
      }
#pragma unroll
      for (int j = 0; j < NN; j++) {
        int r = wn0 + j * 16 + l16;
        bfr[j] = *(const bf16x8*)&Bs[r * 64 + ((c * 4 + quad) ^ (r & 7)) * 8];
      }
#pragma unroll
      for (int i = 0; i < NM; i++)
#pragma unroll
        for (int j = 0; j < NN; j++)
          acc[i][j] = MFMA16(af[i], bfr[j], acc[i][j]);
    }
    __syncthreads();
  }

  bf16* dst = part + (size_t)blockIdx.z * (4096 * 1024);
#pragma unroll
  for (int half = 0; half < 2; half++) {
    if ((wave >> 1) == half) {
#pragma unroll
      for (int i = 0; i < NM; i++)
#pragma unroll
        for (int j = 0; j < NN; j++)
#pragma unroll
          for (int r = 0; r < 4; r++)
            Cs[(i * 16 + quad * 4 + r) * LDC + wn0 + j * 16 + l16] =
                (bf16)acc[i][j][r];
    }
    __syncthreads();
    const int c0 = (tid & 15) * 8;
#pragma unroll
    for (int it = 0; it < 4; it++) {
      int row = (tid >> 4) + it * 16;
      *(bf16x8*)&dst[(rowA0 + half * 64 + row) * 1024 + rowB0 + c0] =
          *(const bf16x8*)&Cs[row * LDC + c0];
    }
    __syncthreads();
  }
}

// ---------------------------------------------------------------------------
// out = x + sum of 4 bf16 partials
// ---------------------------------------------------------------------------
__global__ __launch_bounds__(256) void reduce_out(const float* __restrict__ x,
                                                  const bf16* __restrict__ part,
                                                  float* __restrict__ out) {
  const size_t i = ((size_t)blockIdx.x * 256 + threadIdx.x) * 8;
  constexpr size_t SL = 4096 * 1024;
  float r[8];
  float4 x0 = *(const float4*)&x[i];
  float4 x1 = *(const float4*)&x[i + 4];
  r[0] = x0.x; r[1] = x0.y; r[2] = x0.z; r[3] = x0.w;
  r[4] = x1.x; r[5] = x1.y; r[6] = x1.z; r[7] = x1.w;
#pragma unroll
  for (int z = 0; z < 4; z++) {
    bf16x8 p = *(const bf16x8*)&part[z * SL + i];
#pragma unroll
    for (int k = 0; k < 8; k++) r[k] += (float)p[k];
  }
  float4 o0 = {r[0], r[1], r[2], r[3]};
  float4 o1 = {r[4], r[5], r[6], r[7]};
  *(float4*)&out[i] = o0;
  *(float4*)&out[i + 4] = o1;
}

// ---------------------------------------------------------------------------
extern "C" void kernel_launch(void* const* d_in, const int* in_sizes, int n_in,
                              void* d_out, int out_size, void* d_ws, size_t ws_size,
                              hipStream_t stream) {
  const float* x      = (const float*)d_in[0];
  const float* ln_w   = (const float*)d_in[1];
  const float* ln_b   = (const float*)d_in[2];
  const float* w_in   = (const float*)d_in[3];  // [1024,11264]
  const float* w_attn = (const float*)d_in[4];  // [1024,1024]
  const float* w_ff   = (const float*)d_in[5];  // [4096,1024]
  float* out = (float*)d_out;
  char* ws = (char*)d_ws;

  bf16* wt_in = (bf16*)(ws);                 // [11264][1024] 23068672 B
  bf16* wtcat = (bf16*)(ws + 23068672);      // [1024][5120]  10485760 B
  bf16* xn    = (bf16*)(ws + 33554432);      // [4096][1024]   8388608 B
  bf16* proj  = (bf16*)(ws + 41943040);      // [4096][3072]  25165824 B
  bf16* part  = (bf16*)(ws + 67108864);      // 4x[4096][1024] 33554432 B
  bf16* vt    = (bf16*)(ws + 100663296);     // [32][64][2048]  8388608 B
  bf16* hcat  = (bf16*)(ws + 134217728);     // [4096][5120]  41943040 B

  prep<<<20480, 256, 0, stream>>>(w_in, w_attn, w_ff, wt_in, wtcat,
                                  x, ln_w, ln_b, xn);
  gemm_proj<<<dim3(44, 16), 512, 0, stream>>>(xn, wt_in, proj, hcat);
  vtrans<<<dim3(32, 16, 2), 256, 0, stream>>>(proj, vt);
  flash_attn<<<dim3(32, 16, 2), 256, 0, stream>>>(proj, vt, hcat);
  gemm_out<<<dim3(8, 32, 4), 256, 0, stream>>>(hcat, wtcat, part);
  reduce_out<<<2048, 256, 0, stream>>>(x, part, out);
}

// Round 3
// 387.328 us; speedup vs baseline: 1.0374x; 1.0374x over previous
//
#include <hip/hip_runtime.h>
#include <hip/hip_bf16.h>
#include <cstdint>
#include <cstddef>

typedef __bf16 bf16;
typedef __bf16 bf16x8 __attribute__((ext_vector_type(8)));
typedef float f32x4 __attribute__((ext_vector_type(4)));

#define MFMA16(a, b, c) __builtin_amdgcn_mfma_f32_16x16x32_bf16(a, b, c, 0, 0, 0)

#define GLOBAL_LOAD_LDS16(gptr, lptr)                                          \
  __builtin_amdgcn_global_load_lds(                                            \
      (const __attribute__((address_space(1))) void*)(gptr),                   \
      (__attribute__((address_space(3))) void*)(lptr), 16, 0, 0)

// ---------------------------------------------------------------------------
// prep: blocks 0..16383 = weight transpose+convert; 16384..20479 = LayerNorm.
// ---------------------------------------------------------------------------
__global__ __launch_bounds__(256) void prep(const float* __restrict__ w_in,
                                            const float* __restrict__ w_attn,
                                            const float* __restrict__ w_ff,
                                            bf16* __restrict__ wt_in,
                                            bf16* __restrict__ wtcat,
                                            const float* __restrict__ x,
                                            const float* __restrict__ ln_w,
                                            const float* __restrict__ ln_b,
                                            bf16* __restrict__ xn) {
  __shared__ __align__(16) char sm[4352];
  if (blockIdx.x < 16384) {
    float(*t)[33] = (float(*)[33])sm;
    int id = blockIdx.x;
    const float* src; bf16* dst;
    int srcN, srccol0, LDO, mode, obase, goff, kcol0, ntn;
    if (id < 3072) {
      src = w_in; dst = wt_in; srcN = 11264; srccol0 = 0; LDO = 1024;
      mode = 0; obase = 0; goff = 0; kcol0 = 0; ntn = 96;
    } else if (id < 7168) {
      id -= 3072; src = w_in; dst = wt_in; srcN = 11264; srccol0 = 3072;
      LDO = 1024; mode = 1; obase = 3072; goff = 0; kcol0 = 0; ntn = 128;
    } else if (id < 11264) {
      id -= 7168; src = w_in; dst = wt_in; srcN = 11264; srccol0 = 7168;
      LDO = 1024; mode = 1; obase = 3072; goff = 64; kcol0 = 0; ntn = 128;
    } else if (id < 12288) {
      id -= 11264; src = w_attn; dst = wtcat; srcN = 1024; srccol0 = 0;
      LDO = 5120; mode = 0; obase = 0; goff = 0; kcol0 = 0; ntn = 32;
    } else {
      id -= 12288; src = w_ff; dst = wtcat; srcN = 1024; srccol0 = 0;
      LDO = 5120; mode = 0; obase = 0; goff = 0; kcol0 = 1024; ntn = 32;
    }
    const int n0 = (id % ntn) * 32, k0 = (id / ntn) * 32;
    const int tx = threadIdx.x & 31, ty = threadIdx.x >> 5;
    for (int i = ty; i < 32; i += 8)
      t[i][tx] = src[(size_t)(k0 + i) * srcN + srccol0 + n0 + tx];
    __syncthreads();
    for (int i = ty; i < 32; i += 8) {
      int n = n0 + i;
      int orow = mode ? (obase + ((n >> 6) << 7) + goff + (n & 63)) : (obase + n);
      dst[(size_t)orow * LDO + kcol0 + k0 + tx] = (bf16)t[tx][i];
    }
  } else {
    float* rs = (float*)sm;          // [256]
    float* rss = rs + 256;           // [256]
    const int row = blockIdx.x - 16384;
    const int tid = threadIdx.x;
    const float* xr = x + (size_t)row * 1024;
    float4 v = *(const float4*)&xr[tid * 4];
    float s = v.x + v.y + v.z + v.w;
    float ss = v.x * v.x + v.y * v.y + v.z * v.z + v.w * v.w;
    rs[tid] = s; rss[tid] = ss;
    __syncthreads();
    for (int off = 128; off > 0; off >>= 1) {
      if (tid < off) { rs[tid] += rs[tid + off]; rss[tid] += rss[tid + off]; }
      __syncthreads();
    }
    const float mean = rs[0] * (1.f / 1024.f);
    const float var = rss[0] * (1.f / 1024.f) - mean * mean;
    const float rstd = rsqrtf(var + 1e-5f);
    const float* vp = (const float*)&v;
    for (int i = 0; i < 4; i++) {
      int c = tid * 4 + i;
      xn[(size_t)row * 1024 + c] = (bf16)((vp[i] - mean) * rstd * ln_w[c] + ln_b[c]);
    }
  }
}

// ---------------------------------------------------------------------------
// Flash attention (fixed-max softmax), 128-key tiles, global_load_lds +
// XOR-swizzled LDS. Row-sum kept as per-lane partials; ONE cross-lane
// reduce at kernel end (softmax l is linear under fixed max).
// ---------------------------------------------------------------------------
__global__ __launch_bounds__(256) void flash_attn(const bf16* __restrict__ proj,
                                                  const bf16* __restrict__ vt,
                                                  bf16* __restrict__ hcat) {
  __shared__ __align__(16) char smem[50176];
  bf16* Ks = (bf16*)smem;                  // [128][64] swizzled
  bf16* Vs = (bf16*)(smem + 16384);        // [64][128] swizzled
  bf16* Ps = (bf16*)(smem + 32768);        // [4][16][136]
  const int tid = threadIdx.x;
  const int wave = tid >> 6, lane = tid & 63;
  const int quad = lane >> 4, l16 = lane & 15;
  const int q0 = blockIdx.x * 64;
  const int h = blockIdx.y, b = blockIdx.z;
  constexpr size_t LDP = 3072;
  const bf16* Qb = proj + (size_t)b * 2048 * LDP + h * 64;
  const bf16* Kb = proj + (size_t)b * 2048 * LDP + 1024 + h * 64;
  const bf16* Vt = vt + (size_t)(b * 16 + h) * 64 * 2048;

  const int qrow = q0 + wave * 16 + l16;
  bf16x8 aq0r = *(const bf16x8*)&Qb[(size_t)qrow * LDP + quad * 8];
  bf16x8 aq1r = *(const bf16x8*)&Qb[(size_t)qrow * LDP + 32 + quad * 8];
  bf16x8 aq0, aq1;
#pragma unroll
  for (int i = 0; i < 8; i++) {
    aq0[i] = (bf16)((float)aq0r[i] * 0.125f);
    aq1[i] = (bf16)((float)aq1r[i] * 0.125f);
  }

  f32x4 O[4] = {};
  float plrow[4] = {0.f, 0.f, 0.f, 0.f};  // per-lane partial row-sums

  const int krow_ = wave * 8 + (lane >> 3);
  const int kq_ = ((lane & 7) ^ (krow_ & 7)) * 8;
  const int vrow_ = wave * 4 + (lane >> 4);
  const int vq_ = ((lane & 15) ^ (vrow_ & 15)) * 8;

  for (int j0 = 0; j0 < 2048; j0 += 128) {
#pragma unroll
    for (int p = 0; p < 4; p++) {
      int kr = p * 32 + krow_;
      GLOBAL_LOAD_LDS16(&Kb[(size_t)(j0 + kr) * LDP + kq_],
                        &Ks[kr * 64 + (lane & 7) * 8]);
      int vr = p * 16 + vrow_;
      GLOBAL_LOAD_LDS16(&Vt[(size_t)vr * 2048 + j0 + vq_],
                        &Vs[vr * 128 + (lane & 15) * 8]);
    }
    __syncthreads();

    f32x4 sa[8];
#pragma unroll
    for (int nt = 0; nt < 8; nt++) {
      int r = nt * 16 + l16;
      bf16x8 bk0 = *(const bf16x8*)&Ks[r * 64 + (quad ^ (r & 7)) * 8];
      bf16x8 bk1 = *(const bf16x8*)&Ks[r * 64 + ((quad + 4) ^ (r & 7)) * 8];
      f32x4 t = {};
      t = MFMA16(aq0, bk0, t);
      sa[nt] = MFMA16(aq1, bk1, t);
    }

    bf16* Pw = Ps + wave * (16 * 136);
#pragma unroll
    for (int r = 0; r < 4; r++) {
      bf16* pr = &Pw[(quad * 4 + r) * 136];
      float ts = 0.f;
#pragma unroll
      for (int nt = 0; nt < 8; nt++) {
        float p = __expf(sa[nt][r]);
        pr[nt * 16 + l16] = (bf16)p;
        ts += p;
      }
      plrow[r] += ts;  // defer cross-lane reduce to epilogue
    }

#pragma unroll
    for (int kg = 0; kg < 4; kg++) {
      bf16x8 aP = *(const bf16x8*)&Pw[l16 * 136 + kg * 32 + quad * 8];
#pragma unroll
      for (int nb = 0; nb < 4; nb++) {
        int vrr = nb * 16 + l16;
        int vsl = ((kg * 4 + quad) ^ (vrr & 15)) * 8;
        bf16x8 bv = *(const bf16x8*)&Vs[vrr * 128 + vsl];
        O[nb] = MFMA16(aP, bv, O[nb]);
      }
    }
    __syncthreads();
  }

#pragma unroll
  for (int r = 0; r < 4; r++) {
    float ts = plrow[r];
#pragma unroll
    for (int d = 1; d < 16; d <<= 1) ts += __shfl_xor(ts, d, 64);
    float inv = 1.f / ts;
    size_t row = (size_t)b * 2048 + q0 + wave * 16 + quad * 4 + r;
#pragma unroll
    for (int nb = 0; nb < 4; nb++)
      hcat[row * 5120 + h * 64 + nb * 16 + l16] = (bf16)(O[nb][r] * inv);
  }
}

// ---------------------------------------------------------------------------
// proj GEMM, v4: v2-proven coarse counted-vmcnt loop (256x256, BK=32,
// 3-buffer LDS, stage kt+2, vmcnt(4)/tile, setprio around MFMA cluster).
// Epilogue split: x<8 -> plain Q/K -> proj; x in [8,12) -> V written
// TRANSPOSED straight to vt (vtrans kernel fused away; proj V never
// written, nothing reads it); x>=12 -> ff|gate gelu -> hcat.
// ---------------------------------------------------------------------------
__global__ __launch_bounds__(512, 2) void gemm_proj(const bf16* __restrict__ A,
                                                    const bf16* __restrict__ Bt,
                                                    bf16* __restrict__ proj,
                                                    bf16* __restrict__ hcat,
                                                    bf16* __restrict__ vt) {
  constexpr int K = 1024, NT = 32;
  __shared__ __align__(16) char smem[98304];   // 3 x (As 16K + Bs 16K)
  const int tid = threadIdx.x;
  const int wave = tid >> 6, lane = tid & 63;
  const int quad = lane >> 4, l16 = lane & 15;
  const int wm0 = (wave >> 2) * 128, wn0 = (wave & 3) * 64;
  const size_t rowA0 = (size_t)blockIdx.y * 256;
  const size_t rowB0 = (size_t)blockIdx.x * 256;
  const bf16* Ag = A + rowA0 * K;
  const bf16* Bg = Bt + rowB0 * K;

  const int srow = tid >> 2;
  const int sslot = tid & 3;
  const int rslot = (quad ^ ((l16 >> 1) & 3)) * 8;

  f32x4 acc[8][4] = {};

  auto STAGE = [&](int kt, int buf) {
    bf16* As = (bf16*)(smem + buf * 32768);
    bf16* Bs = As + 256 * 32;
    const int k0 = kt * 32;
#pragma unroll
    for (int p = 0; p < 2; p++) {
      int r = p * 128 + srow;
      int kq = (sslot ^ ((r >> 1) & 3)) * 8;
      GLOBAL_LOAD_LDS16(&Ag[(size_t)r * K + k0 + kq], &As[r * 32 + sslot * 8]);
      GLOBAL_LOAD_LDS16(&Bg[(size_t)r * K + k0 + kq], &Bs[r * 32 + sslot * 8]);
    }
  };

  STAGE(0, 0);
  STAGE(1, 1);
  asm volatile("s_waitcnt vmcnt(4)" ::: "memory");  // kt0 landed, kt1 in flight
  __builtin_amdgcn_s_barrier();
  asm volatile("" ::: "memory");

  int cbuf = 0, sbuf = 2;
#pragma unroll 1
  for (int kt = 0; kt < NT; kt++) {
    if (kt + 2 < NT) STAGE(kt + 2, sbuf);
    const bf16* As = (const bf16*)(smem + cbuf * 32768);
    const bf16* Bs = As + 256 * 32;
    bf16x8 bfr[4];
#pragma unroll
    for (int j = 0; j < 4; j++)
      bfr[j] = *(const bf16x8*)&Bs[(wn0 + j * 16 + l16) * 32 + rslot];
#pragma unroll
    for (int ih = 0; ih < 2; ih++) {
      bf16x8 af[4];
#pragma unroll
      for (int i = 0; i < 4; i++)
        af[i] = *(const bf16x8*)&As[(wm0 + (ih * 4 + i) * 16 + l16) * 32 + rslot];
      __builtin_amdgcn_s_setprio(1);
#pragma unroll
      for (int i = 0; i < 4; i++)
#pragma unroll
        for (int j = 0; j < 4; j++)
          acc[ih * 4 + i][j] = MFMA16(af[i], bfr[j], acc[ih * 4 + i][j]);
      __builtin_amdgcn_s_setprio(0);
    }
    if (kt + 2 < NT) {
      asm volatile("s_waitcnt vmcnt(4)" ::: "memory");  // kt+1 landed
    } else {
      asm volatile("s_waitcnt vmcnt(0)" ::: "memory");  // tail drain
    }
    __builtin_amdgcn_s_barrier();
    asm volatile("" ::: "memory");
    cbuf = (cbuf == 2) ? 0 : cbuf + 1;
    sbuf = (sbuf == 2) ? 0 : sbuf + 1;
  }

  // epilogue: two 128-row halves through LDS
  {
    const int xb = (int)blockIdx.x;
    const int T2 = xb - 12;
    bf16* Cs = (bf16*)smem;          // [128][264]
    constexpr int LDC2 = 264;
#pragma unroll 1
    for (int h = 0; h < 2; h++) {
      if ((wave >> 2) == h) {
#pragma unroll
        for (int i = 0; i < 8; i++)
#pragma unroll
          for (int j = 0; j < 4; j++)
#pragma unroll
            for (int r = 0; r < 4; r++)
              Cs[(i * 16 + quad * 4 + r) * LDC2 + wn0 + j * 16 + l16] =
                  (bf16)acc[i][j][r];
      }
      __syncthreads();
      if (xb < 8) {
        // Q/K tiles -> proj
#pragma unroll
        for (int it = 0; it < 8; it++) {
          int idx = it * 512 + tid;          // 128 rows x 32 chunks
          int row = idx >> 5, ch = (idx & 31) * 8;
          *(bf16x8*)&proj[(rowA0 + h * 128 + row) * 3072 + rowB0 + ch] =
              *(const bf16x8*)&Cs[row * LDC2 + ch];
        }
      } else if (T2 < 0) {
        // V tiles -> vt transposed: vt[(b*16+head)*64+d][s]
        const int g0 = (int)rowA0 + h * 128;   // global row base (b*2048+s)
        const int bb = g0 >> 11, sloc0 = g0 & 2047;
        const int hb = (xb - 8) * 4;           // head base for this tile
        bf16* vtb = vt + ((size_t)(bb * 16 + hb) * 64) * 2048 + sloc0;
#pragma unroll
        for (int it = 0; it < 8; it++) {
          int u = it * 512 + tid;              // 4096 units
          int col = u & 255, sc = u >> 8;      // col = head*64+d, sc = s-chunk
          bf16x8 o;
#pragma unroll
          for (int k = 0; k < 8; k++) o[k] = Cs[(sc * 8 + k) * LDC2 + col];
          *(bf16x8*)&vtb[(size_t)col * 2048 + sc * 8] = o;
        }
      } else {
        // ff|gate gelu -> hcat
#pragma unroll
        for (int it = 0; it < 4; it++) {
          int idx = it * 512 + tid;          // 128 rows x 2 pairs x 8 chunks
          int row = idx >> 4;
          int p = (idx >> 3) & 1, c8 = (idx & 7) * 8;
          bf16x8 f = *(const bf16x8*)&Cs[row * LDC2 + p * 128 + c8];
          bf16x8 g = *(const bf16x8*)&Cs[row * LDC2 + p * 128 + 64 + c8];
          bf16x8 o;
#pragma unroll
          for (int i = 0; i < 8; i++) {
            float xg = (float)g[i];
            float u = 0.7978845608f * (xg + 0.044715f * xg * xg * xg);
            float gl = xg / (1.f + __expf(-2.f * u));
            o[i] = (bf16)((float)f[i] * gl);
          }
          *(bf16x8*)&hcat[(rowA0 + h * 128 + row) * 5120 + 1024 +
                          (2 * T2 + p) * 64 + c8] = o;
        }
      }
      __syncthreads();
    }
  }
}

// ---------------------------------------------------------------------------
// Output GEMM (R8-proven): split-K=4, BK=64, swizzled LDS, bf16 partials.
// ---------------------------------------------------------------------------
__global__ __launch_bounds__(256) void gemm_out(const bf16* __restrict__ A,
                                                const bf16* __restrict__ Bt,
                                                bf16* __restrict__ part) {
  constexpr int LDAB = 5120, LDC = 136;
  __shared__ __align__(16) char smem[32768];
  bf16* As = (bf16*)smem;
  bf16* Bs = As + 128 * 64;
  bf16* Cs = (bf16*)smem;
  const int tid = threadIdx.x;
  const int wave = tid >> 6, lane = tid & 63;
  const int quad = lane >> 4, l16 = lane & 15;
  constexpr int NM = 4, NN = 4;
  const int wm0 = (wave >> 1) * 64, wn0 = (wave & 1) * 64;
  const size_t rowA0 = (size_t)blockIdx.y * 128;
  const size_t rowB0 = (size_t)blockIdx.x * 128;
  const int kbeg = blockIdx.z * 1280, kend = kbeg + 1280;

  const int srow = tid >> 3;
  const int sq = ((tid & 7) ^ (srow & 7)) * 8;
  const int sslot = (tid & 7) * 8;

  f32x4 acc[NM][NN] = {};

  for (int k0 = kbeg; k0 < kend; k0 += 64) {
#pragma unroll
    for (int p = 0; p < 4; p++) {
      int r = p * 32 + srow;
      GLOBAL_LOAD_LDS16(&A[(rowA0 + r) * LDAB + k0 + sq], &As[r * 64 + sslot]);
      GLOBAL_LOAD_LDS16(&Bt[(rowB0 + r) * LDAB + k0 + sq], &Bs[r * 64 + sslot]);
    }
    __syncthreads();
#pragma unroll
    for (int c = 0; c < 2; c++) {
      bf16x8 af[NM], bfr[NN];
#pragma unroll
      for (int i = 0; i < NM; i++) {
        int r = wm0 + i * 16 + l16;
        af[i] = *(const bf16x8*)&As[r * 64 + ((c * 4 + quad) ^ (r & 7)) * 8];
      }
#pragma unroll
      for (int j = 0; j < NN; j++) {
        int r = wn0 + j * 16 + l16;
        bfr[j] = *(const bf16x8*)&Bs[r * 64 + ((c * 4 + quad) ^ (r & 7)) * 8];
      }
#pragma unroll
      for (int i = 0; i < NM; i++)
#pragma unroll
        for (int j = 0; j < NN; j++)
          acc[i][j] = MFMA16(af[i], bfr[j], acc[i][j]);
    }
    __syncthreads();
  }

  bf16* dst = part + (size_t)blockIdx.z * (4096 * 1024);
#pragma unroll
  for (int half = 0; half < 2; half++) {
    if ((wave >> 1) == half) {
#pragma unroll
      for (int i = 0; i < NM; i++)
#pragma unroll
        for (int j = 0; j < NN; j++)
#pragma unroll
          for (int r = 0; r < 4; r++)
            Cs[(i * 16 + quad * 4 + r) * LDC + wn0 + j * 16 + l16] =
                (bf16)acc[i][j][r];
    }
    __syncthreads();
    const int c0 = (tid & 15) * 8;
#pragma unroll
    for (int it = 0; it < 4; it++) {
      int row = (tid >> 4) + it * 16;
      *(bf16x8*)&dst[(rowA0 + half * 64 + row) * 1024 + rowB0 + c0] =
          *(const bf16x8*)&Cs[row * LDC + c0];
    }
    __syncthreads();
  }
}

// ---------------------------------------------------------------------------
// out = x + sum of 4 bf16 partials
// ---------------------------------------------------------------------------
__global__ __launch_bounds__(256) void reduce_out(const float* __restrict__ x,
                                                  const bf16* __restrict__ part,
                                                  float* __restrict__ out) {
  const size_t i = ((size_t)blockIdx.x * 256 + threadIdx.x) * 8;
  constexpr size_t SL = 4096 * 1024;
  float r[8];
  float4 x0 = *(const float4*)&x[i];
  float4 x1 = *(const float4*)&x[i + 4];
  r[0] = x0.x; r[1] = x0.y; r[2] = x0.z; r[3] = x0.w;
  r[4] = x1.x; r[5] = x1.y; r[6] = x1.z; r[7] = x1.w;
#pragma unroll
  for (int z = 0; z < 4; z++) {
    bf16x8 p = *(const bf16x8*)&part[z * SL + i];
#pragma unroll
    for (int k = 0; k < 8; k++) r[k] += (float)p[k];
  }
  float4 o0 = {r[0], r[1], r[2], r[3]};
  float4 o1 = {r[4], r[5], r[6], r[7]};
  *(float4*)&out[i] = o0;
  *(float4*)&out[i + 4] = o1;
}

// ---------------------------------------------------------------------------
extern "C" void kernel_launch(void* const* d_in, const int* in_sizes, int n_in,
                              void* d_out, int out_size, void* d_ws, size_t ws_size,
                              hipStream_t stream) {
  const float* x      = (const float*)d_in[0];
  const float* ln_w   = (const float*)d_in[1];
  const float* ln_b   = (const float*)d_in[2];
  const float* w_in   = (const float*)d_in[3];  // [1024,11264]
  const float* w_attn = (const float*)d_in[4];  // [1024,1024]
  const float* w_ff   = (const float*)d_in[5];  // [4096,1024]
  float* out = (float*)d_out;
  char* ws = (char*)d_ws;

  bf16* wt_in = (bf16*)(ws);                 // [11264][1024] 23068672 B
  bf16* wtcat = (bf16*)(ws + 23068672);      // [1024][5120]  10485760 B
  bf16* xn    = (bf16*)(ws + 33554432);      // [4096][1024]   8388608 B
  bf16* proj  = (bf16*)(ws + 41943040);      // [4096][3072]  25165824 B
  bf16* part  = (bf16*)(ws + 67108864);      // 4x[4096][1024] 33554432 B
  bf16* vt    = (bf16*)(ws + 100663296);     // [32][64][2048]  8388608 B
  bf16* hcat  = (bf16*)(ws + 134217728);     // [4096][5120]  41943040 B

  prep<<<20480, 256, 0, stream>>>(w_in, w_attn, w_ff, wt_in, wtcat,
                                  x, ln_w, ln_b, xn);
  gemm_proj<<<dim3(44, 16), 512, 0, stream>>>(xn, wt_in, proj, hcat, vt);
  flash_attn<<<dim3(32, 16, 2), 256, 0, stream>>>(proj, vt, hcat);
  gemm_out<<<dim3(8, 32, 4), 256, 0, stream>>>(hcat, wtcat, part);
  reduce_out<<<2048, 256, 0, stream>>>(x, part, out);
}

// Round 4
// 378.387 us; speedup vs baseline: 1.0619x; 1.0236x over previous
//
#include <hip/hip_runtime.h>
#include <hip/hip_bf16.h>
#include <cstdint>
#include <cstddef>

typedef __bf16 bf16;
typedef __bf16 bf16x8 __attribute__((ext_vector_type(8)));
typedef float f32x4 __attribute__((ext_vector_type(4)));

#define MFMA16(a, b, c) __builtin_amdgcn_mfma_f32_16x16x32_bf16(a, b, c, 0, 0, 0)

#define GLOBAL_LOAD_LDS16(gptr, lptr)                                          \
  __builtin_amdgcn_global_load_lds(                                            \
      (const __attribute__((address_space(1))) void*)(gptr),                   \
      (__attribute__((address_space(3))) void*)(lptr), 16, 0, 0)

// ---------------------------------------------------------------------------
// prep v2: blocks 0..4095 = 64x64 vectorized weight transpose+convert
// (coalesced float loads, bf16x8 stores); blocks 4096..8191 = LayerNorm.
// wt_in row map: n<3072 -> n; ff (n in [3072,7168)) -> 3072+((m>>6)<<7)+(m&63);
// gate (n>=7168) -> same +64.  64-aligned n-tiles map to contiguous dst rows.
// ---------------------------------------------------------------------------
__global__ __launch_bounds__(256) void prep(const float* __restrict__ w_in,
                                            const float* __restrict__ w_attn,
                                            const float* __restrict__ w_ff,
                                            bf16* __restrict__ wt_in,
                                            bf16* __restrict__ wtcat,
                                            const float* __restrict__ x,
                                            const float* __restrict__ ln_w,
                                            const float* __restrict__ ln_b,
                                            bf16* __restrict__ xn) {
  __shared__ __align__(16) float t[64][65];   // 16.6 KB
  const int tid = threadIdx.x;
  if (blockIdx.x < 4096) {
    int id = blockIdx.x;
    const float* src; bf16* dst;
    int srcN, n0, k0, kcol0;
    size_t LDO;
    bool win;
    if (id < 2816) {
      src = w_in; dst = wt_in; srcN = 11264; LDO = 1024;
      n0 = (id % 176) * 64; k0 = (id / 176) * 64; kcol0 = 0; win = true;
    } else if (id < 3072) {
      id -= 2816; src = w_attn; dst = wtcat; srcN = 1024; LDO = 5120;
      n0 = (id % 16) * 64; k0 = (id / 16) * 64; kcol0 = 0; win = false;
    } else {
      id -= 3072; src = w_ff; dst = wtcat; srcN = 1024; LDO = 5120;
      n0 = (id % 16) * 64; k0 = (id / 16) * 64; kcol0 = 1024; win = false;
    }
    // dst row base for this 64-wide n tile (contiguous 64 rows)
    int drow0;
    if (!win || n0 < 3072) {
      drow0 = n0;
    } else if (n0 < 7168) {
      int m = n0 - 3072; drow0 = 3072 + ((m >> 6) << 7);
    } else {
      int m = n0 - 7168; drow0 = 3072 + ((m >> 6) << 7) + 64;
    }
#pragma unroll
    for (int i = 0; i < 16; i++) {
      int k = i * 4 + (tid >> 6), n = tid & 63;
      t[k][n] = src[(size_t)(k0 + k) * srcN + n0 + n];
    }
    __syncthreads();
#pragma unroll
    for (int j = 0; j < 2; j++) {
      int n = j * 32 + (tid >> 3), kc = (tid & 7) * 8;
      bf16x8 o;
#pragma unroll
      for (int u = 0; u < 8; u++) o[u] = (bf16)t[kc + u][n];
      *(bf16x8*)&dst[(size_t)(drow0 + n) * LDO + kcol0 + k0 + kc] = o;
    }
  } else {
    __shared__ float rs[256], rss[256];
    const int row = blockIdx.x - 4096;
    const float* xr = x + (size_t)row * 1024;
    float4 v = *(const float4*)&xr[tid * 4];
    float s = v.x + v.y + v.z + v.w;
    float ss = v.x * v.x + v.y * v.y + v.z * v.z + v.w * v.w;
    rs[tid] = s; rss[tid] = ss;
    __syncthreads();
    for (int off = 128; off > 0; off >>= 1) {
      if (tid < off) { rs[tid] += rs[tid + off]; rss[tid] += rss[tid + off]; }
      __syncthreads();
    }
    const float mean = rs[0] * (1.f / 1024.f);
    const float var = rss[0] * (1.f / 1024.f) - mean * mean;
    const float rstd = rsqrtf(var + 1e-5f);
    const float* vp = (const float*)&v;
    for (int i = 0; i < 4; i++) {
      int c = tid * 4 + i;
      xn[(size_t)row * 1024 + c] = (bf16)((vp[i] - mean) * rstd * ln_w[c] + ln_b[c]);
    }
  }
}

// ---------------------------------------------------------------------------
// Flash attention (fixed-max softmax), 128-key tiles, global_load_lds +
// XOR-swizzled LDS. Row-sum kept as per-lane partials; ONE cross-lane
// reduce at kernel end (softmax l is linear under fixed max).
// ---------------------------------------------------------------------------
__global__ __launch_bounds__(256) void flash_attn(const bf16* __restrict__ proj,
                                                  const bf16* __restrict__ vt,
                                                  bf16* __restrict__ hcat) {
  __shared__ __align__(16) char smem[50176];
  bf16* Ks = (bf16*)smem;                  // [128][64] swizzled
  bf16* Vs = (bf16*)(smem + 16384);        // [64][128] swizzled
  bf16* Ps = (bf16*)(smem + 32768);        // [4][16][136]
  const int tid = threadIdx.x;
  const int wave = tid >> 6, lane = tid & 63;
  const int quad = lane >> 4, l16 = lane & 15;
  const int q0 = blockIdx.x * 64;
  const int h = blockIdx.y, b = blockIdx.z;
  constexpr size_t LDP = 3072;
  const bf16* Qb = proj + (size_t)b * 2048 * LDP + h * 64;
  const bf16* Kb = proj + (size_t)b * 2048 * LDP + 1024 + h * 64;
  const bf16* Vt = vt + (size_t)(b * 16 + h) * 64 * 2048;

  const int qrow = q0 + wave * 16 + l16;
  bf16x8 aq0r = *(const bf16x8*)&Qb[(size_t)qrow * LDP + quad * 8];
  bf16x8 aq1r = *(const bf16x8*)&Qb[(size_t)qrow * LDP + 32 + quad * 8];
  bf16x8 aq0, aq1;
#pragma unroll
  for (int i = 0; i < 8; i++) {
    aq0[i] = (bf16)((float)aq0r[i] * 0.125f);
    aq1[i] = (bf16)((float)aq1r[i] * 0.125f);
  }

  f32x4 O[4] = {};
  float plrow[4] = {0.f, 0.f, 0.f, 0.f};  // per-lane partial row-sums

  const int krow_ = wave * 8 + (lane >> 3);
  const int kq_ = ((lane & 7) ^ (krow_ & 7)) * 8;
  const int vrow_ = wave * 4 + (lane >> 4);
  const int vq_ = ((lane & 15) ^ (vrow_ & 15)) * 8;

  for (int j0 = 0; j0 < 2048; j0 += 128) {
#pragma unroll
    for (int p = 0; p < 4; p++) {
      int kr = p * 32 + krow_;
      GLOBAL_LOAD_LDS16(&Kb[(size_t)(j0 + kr) * LDP + kq_],
                        &Ks[kr * 64 + (lane & 7) * 8]);
      int vr = p * 16 + vrow_;
      GLOBAL_LOAD_LDS16(&Vt[(size_t)vr * 2048 + j0 + vq_],
                        &Vs[vr * 128 + (lane & 15) * 8]);
    }
    __syncthreads();

    f32x4 sa[8];
#pragma unroll
    for (int nt = 0; nt < 8; nt++) {
      int r = nt * 16 + l16;
      bf16x8 bk0 = *(const bf16x8*)&Ks[r * 64 + (quad ^ (r & 7)) * 8];
      bf16x8 bk1 = *(const bf16x8*)&Ks[r * 64 + ((quad + 4) ^ (r & 7)) * 8];
      f32x4 t = {};
      t = MFMA16(aq0, bk0, t);
      sa[nt] = MFMA16(aq1, bk1, t);
    }

    bf16* Pw = Ps + wave * (16 * 136);
#pragma unroll
    for (int r = 0; r < 4; r++) {
      bf16* pr = &Pw[(quad * 4 + r) * 136];
      float ts = 0.f;
#pragma unroll
      for (int nt = 0; nt < 8; nt++) {
        float p = __expf(sa[nt][r]);
        pr[nt * 16 + l16] = (bf16)p;
        ts += p;
      }
      plrow[r] += ts;  // defer cross-lane reduce to epilogue
    }

#pragma unroll
    for (int kg = 0; kg < 4; kg++) {
      bf16x8 aP = *(const bf16x8*)&Pw[l16 * 136 + kg * 32 + quad * 8];
#pragma unroll
      for (int nb = 0; nb < 4; nb++) {
        int vrr = nb * 16 + l16;
        int vsl = ((kg * 4 + quad) ^ (vrr & 15)) * 8;
        bf16x8 bv = *(const bf16x8*)&Vs[vrr * 128 + vsl];
        O[nb] = MFMA16(aP, bv, O[nb]);
      }
    }
    __syncthreads();
  }

#pragma unroll
  for (int r = 0; r < 4; r++) {
    float ts = plrow[r];
#pragma unroll
    for (int d = 1; d < 16; d <<= 1) ts += __shfl_xor(ts, d, 64);
    float inv = 1.f / ts;
    size_t row = (size_t)b * 2048 + q0 + wave * 16 + quad * 4 + r;
#pragma unroll
    for (int nb = 0; nb < 4; nb++)
      hcat[row * 5120 + h * 64 + nb * 16 + l16] = (bf16)(O[nb][r] * inv);
  }
}

// ---------------------------------------------------------------------------
// proj GEMM, v5: v4 coarse counted-vmcnt loop, prefetch deepened to 3
// K-tiles (4 LDS slots x 32 KB = 128 KB, 1 block/CU unchanged). Steady
// state vmcnt(8) = 2 tiles in flight after wait; tail 4 -> 0.
// Epilogue split: x<8 -> Q/K -> proj; x in [8,12) -> V transposed -> vt;
// x>=12 -> ff|gate gelu -> hcat.
// ---------------------------------------------------------------------------
__global__ __launch_bounds__(512, 2) void gemm_proj(const bf16* __restrict__ A,
                                                    const bf16* __restrict__ Bt,
                                                    bf16* __restrict__ proj,
                                                    bf16* __restrict__ hcat,
                                                    bf16* __restrict__ vt) {
  constexpr int K = 1024, NT = 32;
  __shared__ __align__(16) char smem[131072];   // 4 x (As 16K + Bs 16K)
  const int tid = threadIdx.x;
  const int wave = tid >> 6, lane = tid & 63;
  const int quad = lane >> 4, l16 = lane & 15;
  const int wm0 = (wave >> 2) * 128, wn0 = (wave & 3) * 64;
  const size_t rowA0 = (size_t)blockIdx.y * 256;
  const size_t rowB0 = (size_t)blockIdx.x * 256;
  const bf16* Ag = A + rowA0 * K;
  const bf16* Bg = Bt + rowB0 * K;

  const int srow = tid >> 2;
  const int sslot = tid & 3;
  const int rslot = (quad ^ ((l16 >> 1) & 3)) * 8;

  f32x4 acc[8][4] = {};

  auto STAGE = [&](int kt, int buf) {
    bf16* As = (bf16*)(smem + buf * 32768);
    bf16* Bs = As + 256 * 32;
    const int k0 = kt * 32;
#pragma unroll
    for (int p = 0; p < 2; p++) {
      int r = p * 128 + srow;
      int kq = (sslot ^ ((r >> 1) & 3)) * 8;
      GLOBAL_LOAD_LDS16(&Ag[(size_t)r * K + k0 + kq], &As[r * 32 + sslot * 8]);
      GLOBAL_LOAD_LDS16(&Bg[(size_t)r * K + k0 + kq], &Bs[r * 32 + sslot * 8]);
    }
  };

  STAGE(0, 0);
  STAGE(1, 1);
  STAGE(2, 2);
  asm volatile("s_waitcnt vmcnt(8)" ::: "memory");  // kt0 landed; kt1,kt2 fly
  __builtin_amdgcn_s_barrier();
  asm volatile("" ::: "memory");

#pragma unroll 1
  for (int kt = 0; kt < NT; kt++) {
    if (kt + 3 < NT) STAGE(kt + 3, (kt + 3) & 3);
    const bf16* As = (const bf16*)(smem + (kt & 3) * 32768);
    const bf16* Bs = As + 256 * 32;
    bf16x8 bfr[4];
#pragma unroll
    for (int j = 0; j < 4; j++)
      bfr[j] = *(const bf16x8*)&Bs[(wn0 + j * 16 + l16) * 32 + rslot];
#pragma unroll
    for (int ih = 0; ih < 2; ih++) {
      bf16x8 af[4];
#pragma unroll
      for (int i = 0; i < 4; i++)
        af[i] = *(const bf16x8*)&As[(wm0 + (ih * 4 + i) * 16 + l16) * 32 + rslot];
      __builtin_amdgcn_s_setprio(1);
#pragma unroll
      for (int i = 0; i < 4; i++)
#pragma unroll
        for (int j = 0; j < 4; j++)
          acc[ih * 4 + i][j] = MFMA16(af[i], bfr[j], acc[ih * 4 + i][j]);
      __builtin_amdgcn_s_setprio(0);
    }
    if (kt < NT - 3) {
      asm volatile("s_waitcnt vmcnt(8)" ::: "memory");  // kt+1 landed
    } else if (kt == NT - 3) {
      asm volatile("s_waitcnt vmcnt(4)" ::: "memory");
    } else {
      asm volatile("s_waitcnt vmcnt(0)" ::: "memory");  // tail drain
    }
    __builtin_amdgcn_s_barrier();
    asm volatile("" ::: "memory");
  }

  // epilogue: two 128-row halves through LDS
  {
    const int xb = (int)blockIdx.x;
    const int T2 = xb - 12;
    bf16* Cs = (bf16*)smem;          // [128][264]
    constexpr int LDC2 = 264;
#pragma unroll 1
    for (int h = 0; h < 2; h++) {
      if ((wave >> 2) == h) {
#pragma unroll
        for (int i = 0; i < 8; i++)
#pragma unroll
          for (int j = 0; j < 4; j++)
#pragma unroll
            for (int r = 0; r < 4; r++)
              Cs[(i * 16 + quad * 4 + r) * LDC2 + wn0 + j * 16 + l16] =
                  (bf16)acc[i][j][r];
      }
      __syncthreads();
      if (xb < 8) {
        // Q/K tiles -> proj
#pragma unroll
        for (int it = 0; it < 8; it++) {
          int idx = it * 512 + tid;          // 128 rows x 32 chunks
          int row = idx >> 5, ch = (idx & 31) * 8;
          *(bf16x8*)&proj[(rowA0 + h * 128 + row) * 3072 + rowB0 + ch] =
              *(const bf16x8*)&Cs[row * LDC2 + ch];
        }
      } else if (T2 < 0) {
        // V tiles -> vt transposed: vt[(b*16+head)*64+d][s]
        const int g0 = (int)rowA0 + h * 128;   // global row base (b*2048+s)
        const int bb = g0 >> 11, sloc0 = g0 & 2047;
        const int hb = (xb - 8) * 4;           // head base for this tile
        bf16* vtb = vt + ((size_t)(bb * 16 + hb) * 64) * 2048 + sloc0;
#pragma unroll
        for (int it = 0; it < 8; it++) {
          int u = it * 512 + tid;              // 4096 units
          int col = u & 255, sc = u >> 8;      // col = head*64+d, sc = s-chunk
          bf16x8 o;
#pragma unroll
          for (int k = 0; k < 8; k++) o[k] = Cs[(sc * 8 + k) * LDC2 + col];
          *(bf16x8*)&vtb[(size_t)col * 2048 + sc * 8] = o;
        }
      } else {
        // ff|gate gelu -> hcat
#pragma unroll
        for (int it = 0; it < 4; it++) {
          int idx = it * 512 + tid;          // 128 rows x 2 pairs x 8 chunks
          int row = idx >> 4;
          int p = (idx >> 3) & 1, c8 = (idx & 7) * 8;
          bf16x8 f = *(const bf16x8*)&Cs[row * LDC2 + p * 128 + c8];
          bf16x8 g = *(const bf16x8*)&Cs[row * LDC2 + p * 128 + 64 + c8];
          bf16x8 o;
#pragma unroll
          for (int i = 0; i < 8; i++) {
            float xg = (float)g[i];
            float u = 0.7978845608f * (xg + 0.044715f * xg * xg * xg);
            float gl = xg / (1.f + __expf(-2.f * u));
            o[i] = (bf16)((float)f[i] * gl);
          }
          *(bf16x8*)&hcat[(rowA0 + h * 128 + row) * 5120 + 1024 +
                          (2 * T2 + p) * 64 + c8] = o;
        }
      }
      __syncthreads();
    }
  }
}

// ---------------------------------------------------------------------------
// Output GEMM (R8-proven): split-K=4, BK=64, swizzled LDS, bf16 partials.
// ---------------------------------------------------------------------------
__global__ __launch_bounds__(256) void gemm_out(const bf16* __restrict__ A,
                                                const bf16* __restrict__ Bt,
                                                bf16* __restrict__ part) {
  constexpr int LDAB = 5120, LDC = 136;
  __shared__ __align__(16) char smem[32768];
  bf16* As = (bf16*)smem;
  bf16* Bs = As + 128 * 64;
  bf16* Cs = (bf16*)smem;
  const int tid = threadIdx.x;
  const int wave = tid >> 6, lane = tid & 63;
  const int quad = lane >> 4, l16 = lane & 15;
  constexpr int NM = 4, NN = 4;
  const int wm0 = (wave >> 1) * 64, wn0 = (wave & 1) * 64;
  const size_t rowA0 = (size_t)blockIdx.y * 128;
  const size_t rowB0 = (size_t)blockIdx.x * 128;
  const int kbeg = blockIdx.z * 1280, kend = kbeg + 1280;

  const int srow = tid >> 3;
  const int sq = ((tid & 7) ^ (srow & 7)) * 8;
  const int sslot = (tid & 7) * 8;

  f32x4 acc[NM][NN] = {};

  for (int k0 = kbeg; k0 < kend; k0 += 64) {
#pragma unroll
    for (int p = 0; p < 4; p++) {
      int r = p * 32 + srow;
      GLOBAL_LOAD_LDS16(&A[(rowA0 + r) * LDAB + k0 + sq], &As[r * 64 + sslot]);
      GLOBAL_LOAD_LDS16(&Bt[(rowB0 + r) * LDAB + k0 + sq], &Bs[r * 64 + sslot]);
    }
    __syncthreads();
#pragma unroll
    for (int c = 0; c < 2; c++) {
      bf16x8 af[NM], bfr[NN];
#pragma unroll
      for (int i = 0; i < NM; i++) {
        int r = wm0 + i * 16 + l16;
        af[i] = *(const bf16x8*)&As[r * 64 + ((c * 4 + quad) ^ (r & 7)) * 8];
      }
#pragma unroll
      for (int j = 0; j < NN; j++) {
        int r = wn0 + j * 16 + l16;
        bfr[j] = *(const bf16x8*)&Bs[r * 64 + ((c * 4 + quad) ^ (r & 7)) * 8];
      }
#pragma unroll
      for (int i = 0; i < NM; i++)
#pragma unroll
        for (int j = 0; j < NN; j++)
          acc[i][j] = MFMA16(af[i], bfr[j], acc[i][j]);
    }
    __syncthreads();
  }

  bf16* dst = part + (size_t)blockIdx.z * (4096 * 1024);
#pragma unroll
  for (int half = 0; half < 2; half++) {
    if ((wave >> 1) == half) {
#pragma unroll
      for (int i = 0; i < NM; i++)
#pragma unroll
        for (int j = 0; j < NN; j++)
#pragma unroll
          for (int r = 0; r < 4; r++)
            Cs[(i * 16 + quad * 4 + r) * LDC + wn0 + j * 16 + l16] =
                (bf16)acc[i][j][r];
    }
    __syncthreads();
    const int c0 = (tid & 15) * 8;
#pragma unroll
    for (int it = 0; it < 4; it++) {
      int row = (tid >> 4) + it * 16;
      *(bf16x8*)&dst[(rowA0 + half * 64 + row) * 1024 + rowB0 + c0] =
          *(const bf16x8*)&Cs[row * LDC + c0];
    }
    __syncthreads();
  }
}

// ---------------------------------------------------------------------------
// out = x + sum of 4 bf16 partials
// ---------------------------------------------------------------------------
__global__ __launch_bounds__(256) void reduce_out(const float* __restrict__ x,
                                                  const bf16* __restrict__ part,
                                                  float* __restrict__ out) {
  const size_t i = ((size_t)blockIdx.x * 256 + threadIdx.x) * 8;
  constexpr size_t SL = 4096 * 1024;
  float r[8];
  float4 x0 = *(const float4*)&x[i];
  float4 x1 = *(const float4*)&x[i + 4];
  r[0] = x0.x; r[1] = x0.y; r[2] = x0.z; r[3] = x0.w;
  r[4] = x1.x; r[5] = x1.y; r[6] = x1.z; r[7] = x1.w;
#pragma unroll
  for (int z = 0; z < 4; z++) {
    bf16x8 p = *(const bf16x8*)&part[z * SL + i];
#pragma unroll
    for (int k = 0; k < 8; k++) r[k] += (float)p[k];
  }
  float4 o0 = {r[0], r[1], r[2], r[3]};
  float4 o1 = {r[4], r[5], r[6], r[7]};
  *(float4*)&out[i] = o0;
  *(float4*)&out[i + 4] = o1;
}

// ---------------------------------------------------------------------------
extern "C" void kernel_launch(void* const* d_in, const int* in_sizes, int n_in,
                              void* d_out, int out_size, void* d_ws, size_t ws_size,
                              hipStream_t stream) {
  const float* x      = (const float*)d_in[0];
  const float* ln_w   = (const float*)d_in[1];
  const float* ln_b   = (const float*)d_in[2];
  const float* w_in   = (const float*)d_in[3];  // [1024,11264]
  const float* w_attn = (const float*)d_in[4];  // [1024,1024]
  const float* w_ff   = (const float*)d_in[5];  // [4096,1024]
  float* out = (float*)d_out;
  char* ws = (char*)d_ws;

  bf16* wt_in = (bf16*)(ws);                 // [11264][1024] 23068672 B
  bf16* wtcat = (bf16*)(ws + 23068672);      // [1024][5120]  10485760 B
  bf16* xn    = (bf16*)(ws + 33554432);      // [4096][1024]   8388608 B
  bf16* proj  = (bf16*)(ws + 41943040);      // [4096][3072]  25165824 B
  bf16* part  = (bf16*)(ws + 67108864);      // 4x[4096][1024] 33554432 B
  bf16* vt    = (bf16*)(ws + 100663296);     // [32][64][2048]  8388608 B
  bf16* hcat  = (bf16*)(ws + 134217728);     // [4096][5120]  41943040 B

  prep<<<8192, 256, 0, stream>>>(w_in, w_attn, w_ff, wt_in, wtcat,
                                 x, ln_w, ln_b, xn);
  gemm_proj<<<dim3(44, 16), 512, 0, stream>>>(xn, wt_in, proj, hcat, vt);
  flash_attn<<<dim3(32, 16, 2), 256, 0, stream>>>(proj, vt, hcat);
  gemm_out<<<dim3(8, 32, 4), 256, 0, stream>>>(hcat, wtcat, part);
  reduce_out<<<2048, 256, 0, stream>>>(x, part, out);
}

// Round 5
// 354.001 us; speedup vs baseline: 1.1350x; 1.0689x over previous
//
#include <hip/hip_runtime.h>
#include <hip/hip_bf16.h>
#include <cstdint>
#include <cstddef>

typedef __bf16 bf16;
typedef __bf16 bf16x8 __attribute__((ext_vector_type(8)));
typedef float f32x4 __attribute__((ext_vector_type(4)));

#define MFMA16(a, b, c) __builtin_amdgcn_mfma_f32_16x16x32_bf16(a, b, c, 0, 0, 0)

#define GLOBAL_LOAD_LDS16(gptr, lptr)                                          \
  __builtin_amdgcn_global_load_lds(                                            \
      (const __attribute__((address_space(1))) void*)(gptr),                   \
      (__attribute__((address_space(3))) void*)(lptr), 16, 0, 0)

// ---------------------------------------------------------------------------
// prep v2: blocks 0..4095 = 64x64 vectorized weight transpose+convert
// (coalesced float loads, bf16x8 stores); blocks 4096..8191 = LayerNorm.
// ---------------------------------------------------------------------------
__global__ __launch_bounds__(256) void prep(const float* __restrict__ w_in,
                                            const float* __restrict__ w_attn,
                                            const float* __restrict__ w_ff,
                                            bf16* __restrict__ wt_in,
                                            bf16* __restrict__ wtcat,
                                            const float* __restrict__ x,
                                            const float* __restrict__ ln_w,
                                            const float* __restrict__ ln_b,
                                            bf16* __restrict__ xn) {
  __shared__ __align__(16) float t[64][65];   // 16.6 KB
  const int tid = threadIdx.x;
  if (blockIdx.x < 4096) {
    int id = blockIdx.x;
    const float* src; bf16* dst;
    int srcN, n0, k0, kcol0;
    size_t LDO;
    bool win;
    if (id < 2816) {
      src = w_in; dst = wt_in; srcN = 11264; LDO = 1024;
      n0 = (id % 176) * 64; k0 = (id / 176) * 64; kcol0 = 0; win = true;
    } else if (id < 3072) {
      id -= 2816; src = w_attn; dst = wtcat; srcN = 1024; LDO = 5120;
      n0 = (id % 16) * 64; k0 = (id / 16) * 64; kcol0 = 0; win = false;
    } else {
      id -= 3072; src = w_ff; dst = wtcat; srcN = 1024; LDO = 5120;
      n0 = (id % 16) * 64; k0 = (id / 16) * 64; kcol0 = 1024; win = false;
    }
    int drow0;
    if (!win || n0 < 3072) {
      drow0 = n0;
    } else if (n0 < 7168) {
      int m = n0 - 3072; drow0 = 3072 + ((m >> 6) << 7);
    } else {
      int m = n0 - 7168; drow0 = 3072 + ((m >> 6) << 7) + 64;
    }
#pragma unroll
    for (int i = 0; i < 16; i++) {
      int k = i * 4 + (tid >> 6), n = tid & 63;
      t[k][n] = src[(size_t)(k0 + k) * srcN + n0 + n];
    }
    __syncthreads();
#pragma unroll
    for (int j = 0; j < 2; j++) {
      int n = j * 32 + (tid >> 3), kc = (tid & 7) * 8;
      bf16x8 o;
#pragma unroll
      for (int u = 0; u < 8; u++) o[u] = (bf16)t[kc + u][n];
      *(bf16x8*)&dst[(size_t)(drow0 + n) * LDO + kcol0 + k0 + kc] = o;
    }
  } else {
    __shared__ float rs[256], rss[256];
    const int row = blockIdx.x - 4096;
    const float* xr = x + (size_t)row * 1024;
    float4 v = *(const float4*)&xr[tid * 4];
    float s = v.x + v.y + v.z + v.w;
    float ss = v.x * v.x + v.y * v.y + v.z * v.z + v.w * v.w;
    rs[tid] = s; rss[tid] = ss;
    __syncthreads();
    for (int off = 128; off > 0; off >>= 1) {
      if (tid < off) { rs[tid] += rs[tid + off]; rss[tid] += rss[tid + off]; }
      __syncthreads();
    }
    const float mean = rs[0] * (1.f / 1024.f);
    const float var = rss[0] * (1.f / 1024.f) - mean * mean;
    const float rstd = rsqrtf(var + 1e-5f);
    const float* vp = (const float*)&v;
    for (int i = 0; i < 4; i++) {
      int c = tid * 4 + i;
      xn[(size_t)row * 1024 + c] = (bf16)((vp[i] - mean) * rstd * ln_w[c] + ln_b[c]);
    }
  }
}

// ---------------------------------------------------------------------------
// Flash attention (fixed-max softmax), 128-key tiles, global_load_lds +
// XOR-swizzled LDS. Row-sum kept as per-lane partials; ONE cross-lane
// reduce at kernel end (softmax l is linear under fixed max).
// ---------------------------------------------------------------------------
__global__ __launch_bounds__(256) void flash_attn(const bf16* __restrict__ proj,
                                                  const bf16* __restrict__ vt,
                                                  bf16* __restrict__ hcat) {
  __shared__ __align__(16) char smem[50176];
  bf16* Ks = (bf16*)smem;                  // [128][64] swizzled
  bf16* Vs = (bf16*)(smem + 16384);        // [64][128] swizzled
  bf16* Ps = (bf16*)(smem + 32768);        // [4][16][136]
  const int tid = threadIdx.x;
  const int wave = tid >> 6, lane = tid & 63;
  const int quad = lane >> 4, l16 = lane & 15;
  const int q0 = blockIdx.x * 64;
  const int h = blockIdx.y, b = blockIdx.z;
  constexpr size_t LDP = 3072;
  const bf16* Qb = proj + (size_t)b * 2048 * LDP + h * 64;
  const bf16* Kb = proj + (size_t)b * 2048 * LDP + 1024 + h * 64;
  const bf16* Vt = vt + (size_t)(b * 16 + h) * 64 * 2048;

  const int qrow = q0 + wave * 16 + l16;
  bf16x8 aq0r = *(const bf16x8*)&Qb[(size_t)qrow * LDP + quad * 8];
  bf16x8 aq1r = *(const bf16x8*)&Qb[(size_t)qrow * LDP + 32 + quad * 8];
  bf16x8 aq0, aq1;
#pragma unroll
  for (int i = 0; i < 8; i++) {
    aq0[i] = (bf16)((float)aq0r[i] * 0.125f);
    aq1[i] = (bf16)((float)aq1r[i] * 0.125f);
  }

  f32x4 O[4] = {};
  float plrow[4] = {0.f, 0.f, 0.f, 0.f};  // per-lane partial row-sums

  const int krow_ = wave * 8 + (lane >> 3);
  const int kq_ = ((lane & 7) ^ (krow_ & 7)) * 8;
  const int vrow_ = wave * 4 + (lane >> 4);
  const int vq_ = ((lane & 15) ^ (vrow_ & 15)) * 8;

  for (int j0 = 0; j0 < 2048; j0 += 128) {
#pragma unroll
    for (int p = 0; p < 4; p++) {
      int kr = p * 32 + krow_;
      GLOBAL_LOAD_LDS16(&Kb[(size_t)(j0 + kr) * LDP + kq_],
                        &Ks[kr * 64 + (lane & 7) * 8]);
      int vr = p * 16 + vrow_;
      GLOBAL_LOAD_LDS16(&Vt[(size_t)vr * 2048 + j0 + vq_],
                        &Vs[vr * 128 + (lane & 15) * 8]);
    }
    __syncthreads();

    f32x4 sa[8];
#pragma unroll
    for (int nt = 0; nt < 8; nt++) {
      int r = nt * 16 + l16;
      bf16x8 bk0 = *(const bf16x8*)&Ks[r * 64 + (quad ^ (r & 7)) * 8];
      bf16x8 bk1 = *(const bf16x8*)&Ks[r * 64 + ((quad + 4) ^ (r & 7)) * 8];
      f32x4 t = {};
      t = MFMA16(aq0, bk0, t);
      sa[nt] = MFMA16(aq1, bk1, t);
    }

    bf16* Pw = Ps + wave * (16 * 136);
#pragma unroll
    for (int r = 0; r < 4; r++) {
      bf16* pr = &Pw[(quad * 4 + r) * 136];
      float ts = 0.f;
#pragma unroll
      for (int nt = 0; nt < 8; nt++) {
        float p = __expf(sa[nt][r]);
        pr[nt * 16 + l16] = (bf16)p;
        ts += p;
      }
      plrow[r] += ts;  // defer cross-lane reduce to epilogue
    }

#pragma unroll
    for (int kg = 0; kg < 4; kg++) {
      bf16x8 aP = *(const bf16x8*)&Pw[l16 * 136 + kg * 32 + quad * 8];
#pragma unroll
      for (int nb = 0; nb < 4; nb++) {
        int vrr = nb * 16 + l16;
        int vsl = ((kg * 4 + quad) ^ (vrr & 15)) * 8;
        bf16x8 bv = *(const bf16x8*)&Vs[vrr * 128 + vsl];
        O[nb] = MFMA16(aP, bv, O[nb]);
      }
    }
    __syncthreads();
  }

#pragma unroll
  for (int r = 0; r < 4; r++) {
    float ts = plrow[r];
#pragma unroll
    for (int d = 1; d < 16; d <<= 1) ts += __shfl_xor(ts, d, 64);
    float inv = 1.f / ts;
    size_t row = (size_t)b * 2048 + q0 + wave * 16 + quad * 4 + r;
#pragma unroll
    for (int nb = 0; nb < 4; nb++)
      hcat[row * 5120 + h * 64 + nb * 16 + l16] = (bf16)(O[nb][r] * inv);
  }
}

// ---------------------------------------------------------------------------
// proj GEMM (v4/R3-proven, 121 us): 256x256, BK=32, 3-buffer LDS (96 KB),
// counted-vmcnt depth-2 pipeline, setprio around MFMA cluster.
// Epilogue split: x<8 -> Q/K -> proj; x in [8,12) -> V transposed -> vt;
// x>=12 -> ff|gate gelu -> hcat.
// ---------------------------------------------------------------------------
__global__ __launch_bounds__(512, 2) void gemm_proj(const bf16* __restrict__ A,
                                                    const bf16* __restrict__ Bt,
                                                    bf16* __restrict__ proj,
                                                    bf16* __restrict__ hcat,
                                                    bf16* __restrict__ vt) {
  constexpr int K = 1024, NT = 32;
  __shared__ __align__(16) char smem[98304];   // 3 x (As 16K + Bs 16K)
  const int tid = threadIdx.x;
  const int wave = tid >> 6, lane = tid & 63;
  const int quad = lane >> 4, l16 = lane & 15;
  const int wm0 = (wave >> 2) * 128, wn0 = (wave & 3) * 64;
  const size_t rowA0 = (size_t)blockIdx.y * 256;
  const size_t rowB0 = (size_t)blockIdx.x * 256;
  const bf16* Ag = A + rowA0 * K;
  const bf16* Bg = Bt + rowB0 * K;

  const int srow = tid >> 2;
  const int sslot = tid & 3;
  const int rslot = (quad ^ ((l16 >> 1) & 3)) * 8;

  f32x4 acc[8][4] = {};

  auto STAGE = [&](int kt, int buf) {
    bf16* As = (bf16*)(smem + buf * 32768);
    bf16* Bs = As + 256 * 32;
    const int k0 = kt * 32;
#pragma unroll
    for (int p = 0; p < 2; p++) {
      int r = p * 128 + srow;
      int kq = (sslot ^ ((r >> 1) & 3)) * 8;
      GLOBAL_LOAD_LDS16(&Ag[(size_t)r * K + k0 + kq], &As[r * 32 + sslot * 8]);
      GLOBAL_LOAD_LDS16(&Bg[(size_t)r * K + k0 + kq], &Bs[r * 32 + sslot * 8]);
    }
  };

  STAGE(0, 0);
  STAGE(1, 1);
  asm volatile("s_waitcnt vmcnt(4)" ::: "memory");  // kt0 landed, kt1 in flight
  __builtin_amdgcn_s_barrier();
  asm volatile("" ::: "memory");

  int cbuf = 0, sbuf = 2;
#pragma unroll 1
  for (int kt = 0; kt < NT; kt++) {
    if (kt + 2 < NT) STAGE(kt + 2, sbuf);
    const bf16* As = (const bf16*)(smem + cbuf * 32768);
    const bf16* Bs = As + 256 * 32;
    bf16x8 bfr[4];
#pragma unroll
    for (int j = 0; j < 4; j++)
      bfr[j] = *(const bf16x8*)&Bs[(wn0 + j * 16 + l16) * 32 + rslot];
#pragma unroll
    for (int ih = 0; ih < 2; ih++) {
      bf16x8 af[4];
#pragma unroll
      for (int i = 0; i < 4; i++)
        af[i] = *(const bf16x8*)&As[(wm0 + (ih * 4 + i) * 16 + l16) * 32 + rslot];
      __builtin_amdgcn_s_setprio(1);
#pragma unroll
      for (int i = 0; i < 4; i++)
#pragma unroll
        for (int j = 0; j < 4; j++)
          acc[ih * 4 + i][j] = MFMA16(af[i], bfr[j], acc[ih * 4 + i][j]);
      __builtin_amdgcn_s_setprio(0);
    }
    if (kt + 2 < NT) {
      asm volatile("s_waitcnt vmcnt(4)" ::: "memory");  // kt+1 landed
    } else {
      asm volatile("s_waitcnt vmcnt(0)" ::: "memory");  // tail drain
    }
    __builtin_amdgcn_s_barrier();
    asm volatile("" ::: "memory");
    cbuf = (cbuf == 2) ? 0 : cbuf + 1;
    sbuf = (sbuf == 2) ? 0 : sbuf + 1;
  }

  // epilogue: two 128-row halves through LDS
  {
    const int xb = (int)blockIdx.x;
    const int T2 = xb - 12;
    bf16* Cs = (bf16*)smem;          // [128][264]
    constexpr int LDC2 = 264;
#pragma unroll 1
    for (int h = 0; h < 2; h++) {
      if ((wave >> 2) == h) {
#pragma unroll
        for (int i = 0; i < 8; i++)
#pragma unroll
          for (int j = 0; j < 4; j++)
#pragma unroll
            for (int r = 0; r < 4; r++)
              Cs[(i * 16 + quad * 4 + r) * LDC2 + wn0 + j * 16 + l16] =
                  (bf16)acc[i][j][r];
      }
      __syncthreads();
      if (xb < 8) {
        // Q/K tiles -> proj
#pragma unroll
        for (int it = 0; it < 8; it++) {
          int idx = it * 512 + tid;          // 128 rows x 32 chunks
          int row = idx >> 5, ch = (idx & 31) * 8;
          *(bf16x8*)&proj[(rowA0 + h * 128 + row) * 3072 + rowB0 + ch] =
              *(const bf16x8*)&Cs[row * LDC2 + ch];
        }
      } else if (T2 < 0) {
        // V tiles -> vt transposed: vt[(b*16+head)*64+d][s]
        const int g0 = (int)rowA0 + h * 128;   // global row base (b*2048+s)
        const int bb = g0 >> 11, sloc0 = g0 & 2047;
        const int hb = (xb - 8) * 4;           // head base for this tile
        bf16* vtb = vt + ((size_t)(bb * 16 + hb) * 64) * 2048 + sloc0;
#pragma unroll
        for (int it = 0; it < 8; it++) {
          int u = it * 512 + tid;              // 4096 units
          int col = u & 255, sc = u >> 8;      // col = head*64+d, sc = s-chunk
          bf16x8 o;
#pragma unroll
          for (int k = 0; k < 8; k++) o[k] = Cs[(sc * 8 + k) * LDC2 + col];
          *(bf16x8*)&vtb[(size_t)col * 2048 + sc * 8] = o;
        }
      } else {
        // ff|gate gelu -> hcat
#pragma unroll
        for (int it = 0; it < 4; it++) {
          int idx = it * 512 + tid;          // 128 rows x 2 pairs x 8 chunks
          int row = idx >> 4;
          int p = (idx >> 3) & 1, c8 = (idx & 7) * 8;
          bf16x8 f = *(const bf16x8*)&Cs[row * LDC2 + p * 128 + c8];
          bf16x8 g = *(const bf16x8*)&Cs[row * LDC2 + p * 128 + 64 + c8];
          bf16x8 o;
#pragma unroll
          for (int i = 0; i < 8; i++) {
            float xg = (float)g[i];
            float u = 0.7978845608f * (xg + 0.044715f * xg * xg * xg);
            float gl = xg / (1.f + __expf(-2.f * u));
            o[i] = (bf16)((float)f[i] * gl);
          }
          *(bf16x8*)&hcat[(rowA0 + h * 128 + row) * 5120 + 1024 +
                          (2 * T2 + p) * 64 + c8] = o;
        }
      }
      __syncthreads();
    }
  }
}

// ---------------------------------------------------------------------------
// Output GEMM v2: clone of gemm_proj's proven engine. 256x256 tile, BK=32,
// 3-buffer counted-vmcnt, 8 waves, split-K=4 -> grid dim3(4,16,4) = 256
// blocks = exactly 1 block/CU, zero tail. Per block K-range 1280 (40 tiles).
// ---------------------------------------------------------------------------
__global__ __launch_bounds__(512, 2) void gemm_out(const bf16* __restrict__ A,
                                                   const bf16* __restrict__ Bt,
                                                   bf16* __restrict__ part) {
  constexpr int LDAB = 5120, NT = 40;
  __shared__ __align__(16) char smem[98304];   // 3 x (As 16K + Bs 16K)
  const int tid = threadIdx.x;
  const int wave = tid >> 6, lane = tid & 63;
  const int quad = lane >> 4, l16 = lane & 15;
  const int wm0 = (wave >> 2) * 128, wn0 = (wave & 3) * 64;
  const size_t rowA0 = (size_t)blockIdx.y * 256;
  const size_t rowB0 = (size_t)blockIdx.x * 256;
  const int kbeg = blockIdx.z * 1280;
  const bf16* Ag = A + rowA0 * LDAB + kbeg;
  const bf16* Bg = Bt + rowB0 * LDAB + kbeg;

  const int srow = tid >> 2;
  const int sslot = tid & 3;
  const int rslot = (quad ^ ((l16 >> 1) & 3)) * 8;

  f32x4 acc[8][4] = {};

  auto STAGE = [&](int kt, int buf) {
    bf16* As = (bf16*)(smem + buf * 32768);
    bf16* Bs = As + 256 * 32;
    const int k0 = kt * 32;
#pragma unroll
    for (int p = 0; p < 2; p++) {
      int r = p * 128 + srow;
      int kq = (sslot ^ ((r >> 1) & 3)) * 8;
      GLOBAL_LOAD_LDS16(&Ag[(size_t)r * LDAB + k0 + kq], &As[r * 32 + sslot * 8]);
      GLOBAL_LOAD_LDS16(&Bg[(size_t)r * LDAB + k0 + kq], &Bs[r * 32 + sslot * 8]);
    }
  };

  STAGE(0, 0);
  STAGE(1, 1);
  asm volatile("s_waitcnt vmcnt(4)" ::: "memory");
  __builtin_amdgcn_s_barrier();
  asm volatile("" ::: "memory");

  int cbuf = 0, sbuf = 2;
#pragma unroll 1
  for (int kt = 0; kt < NT; kt++) {
    if (kt + 2 < NT) STAGE(kt + 2, sbuf);
    const bf16* As = (const bf16*)(smem + cbuf * 32768);
    const bf16* Bs = As + 256 * 32;
    bf16x8 bfr[4];
#pragma unroll
    for (int j = 0; j < 4; j++)
      bfr[j] = *(const bf16x8*)&Bs[(wn0 + j * 16 + l16) * 32 + rslot];
#pragma unroll
    for (int ih = 0; ih < 2; ih++) {
      bf16x8 af[4];
#pragma unroll
      for (int i = 0; i < 4; i++)
        af[i] = *(const bf16x8*)&As[(wm0 + (ih * 4 + i) * 16 + l16) * 32 + rslot];
      __builtin_amdgcn_s_setprio(1);
#pragma unroll
      for (int i = 0; i < 4; i++)
#pragma unroll
        for (int j = 0; j < 4; j++)
          acc[ih * 4 + i][j] = MFMA16(af[i], bfr[j], acc[ih * 4 + i][j]);
      __builtin_amdgcn_s_setprio(0);
    }
    if (kt + 2 < NT) {
      asm volatile("s_waitcnt vmcnt(4)" ::: "memory");
    } else {
      asm volatile("s_waitcnt vmcnt(0)" ::: "memory");
    }
    __builtin_amdgcn_s_barrier();
    asm volatile("" ::: "memory");
    cbuf = (cbuf == 2) ? 0 : cbuf + 1;
    sbuf = (sbuf == 2) ? 0 : sbuf + 1;
  }

  // epilogue: two 128-row halves through LDS -> part[z]
  {
    bf16* dst = part + (size_t)blockIdx.z * (4096 * 1024);
    bf16* Cs = (bf16*)smem;          // [128][264]
    constexpr int LDC2 = 264;
#pragma unroll 1
    for (int h = 0; h < 2; h++) {
      if ((wave >> 2) == h) {
#pragma unroll
        for (int i = 0; i < 8; i++)
#pragma unroll
          for (int j = 0; j < 4; j++)
#pragma unroll
            for (int r = 0; r < 4; r++)
              Cs[(i * 16 + quad * 4 + r) * LDC2 + wn0 + j * 16 + l16] =
                  (bf16)acc[i][j][r];
      }
      __syncthreads();
#pragma unroll
      for (int it = 0; it < 8; it++) {
        int idx = it * 512 + tid;          // 128 rows x 32 chunks
        int row = idx >> 5, ch = (idx & 31) * 8;
        *(bf16x8*)&dst[(rowA0 + h * 128 + row) * 1024 + rowB0 + ch] =
            *(const bf16x8*)&Cs[row * LDC2 + ch];
      }
      __syncthreads();
    }
  }
}

// ---------------------------------------------------------------------------
// out = x + sum of 4 bf16 partials
// ---------------------------------------------------------------------------
__global__ __launch_bounds__(256) void reduce_out(const float* __restrict__ x,
                                                  const bf16* __restrict__ part,
                                                  float* __restrict__ out) {
  const size_t i = ((size_t)blockIdx.x * 256 + threadIdx.x) * 8;
  constexpr size_t SL = 4096 * 1024;
  float r[8];
  float4 x0 = *(const float4*)&x[i];
  float4 x1 = *(const float4*)&x[i + 4];
  r[0] = x0.x; r[1] = x0.y; r[2] = x0.z; r[3] = x0.w;
  r[4] = x1.x; r[5] = x1.y; r[6] = x1.z; r[7] = x1.w;
#pragma unroll
  for (int z = 0; z < 4; z++) {
    bf16x8 p = *(const bf16x8*)&part[z * SL + i];
#pragma unroll
    for (int k = 0; k < 8; k++) r[k] += (float)p[k];
  }
  float4 o0 = {r[0], r[1], r[2], r[3]};
  float4 o1 = {r[4], r[5], r[6], r[7]};
  *(float4*)&out[i] = o0;
  *(float4*)&out[i + 4] = o1;
}

// ---------------------------------------------------------------------------
extern "C" void kernel_launch(void* const* d_in, const int* in_sizes, int n_in,
                              void* d_out, int out_size, void* d_ws, size_t ws_size,
                              hipStream_t stream) {
  const float* x      = (const float*)d_in[0];
  const float* ln_w   = (const float*)d_in[1];
  const float* ln_b   = (const float*)d_in[2];
  const float* w_in   = (const float*)d_in[3];  // [1024,11264]
  const float* w_attn = (const float*)d_in[4];  // [1024,1024]
  const float* w_ff   = (const float*)d_in[5];  // [4096,1024]
  float* out = (float*)d_out;
  char* ws = (char*)d_ws;

  bf16* wt_in = (bf16*)(ws);                 // [11264][1024] 23068672 B
  bf16* wtcat = (bf16*)(ws + 23068672);      // [1024][5120]  10485760 B
  bf16* xn    = (bf16*)(ws + 33554432);      // [4096][1024]   8388608 B
  bf16* proj  = (bf16*)(ws + 41943040);      // [4096][3072]  25165824 B
  bf16* part  = (bf16*)(ws + 67108864);      // 4x[4096][1024] 33554432 B
  bf16* vt    = (bf16*)(ws + 100663296);     // [32][64][2048]  8388608 B
  bf16* hcat  = (bf16*)(ws + 134217728);     // [4096][5120]  41943040 B

  prep<<<8192, 256, 0, stream>>>(w_in, w_attn, w_ff, wt_in, wtcat,
                                 x, ln_w, ln_b, xn);
  gemm_proj<<<dim3(44, 16), 512, 0, stream>>>(xn, wt_in, proj, hcat, vt);
  flash_attn<<<dim3(32, 16, 2), 256, 0, stream>>>(proj, vt, hcat);
  gemm_out<<<dim3(4, 16, 4), 512, 0, stream>>>(hcat, wtcat, part);
  reduce_out<<<2048, 256, 0, stream>>>(x, part, out);
}

// Round 6
// 347.947 us; speedup vs baseline: 1.1548x; 1.0174x over previous
//
#include <hip/hip_runtime.h>
#include <hip/hip_bf16.h>
#include <cstdint>
#include <cstddef>

typedef __bf16 bf16;
typedef __bf16 bf16x8 __attribute__((ext_vector_type(8)));
typedef float f32x4 __attribute__((ext_vector_type(4)));

#define MFMA16(a, b, c) __builtin_amdgcn_mfma_f32_16x16x32_bf16(a, b, c, 0, 0, 0)

#define GLOBAL_LOAD_LDS16(gptr, lptr)                                          \
  __builtin_amdgcn_global_load_lds(                                            \
      (const __attribute__((address_space(1))) void*)(gptr),                   \
      (__attribute__((address_space(3))) void*)(lptr), 16, 0, 0)

// ---------------------------------------------------------------------------
// prep v2: blocks 0..4095 = 64x64 vectorized weight transpose+convert
// (coalesced float loads, bf16x8 stores); blocks 4096..8191 = LayerNorm.
// ---------------------------------------------------------------------------
__global__ __launch_bounds__(256) void prep(const float* __restrict__ w_in,
                                            const float* __restrict__ w_attn,
                                            const float* __restrict__ w_ff,
                                            bf16* __restrict__ wt_in,
                                            bf16* __restrict__ wtcat,
                                            const float* __restrict__ x,
                                            const float* __restrict__ ln_w,
                                            const float* __restrict__ ln_b,
                                            bf16* __restrict__ xn) {
  __shared__ __align__(16) float t[64][65];   // 16.6 KB
  const int tid = threadIdx.x;
  if (blockIdx.x < 4096) {
    int id = blockIdx.x;
    const float* src; bf16* dst;
    int srcN, n0, k0, kcol0;
    size_t LDO;
    bool win;
    if (id < 2816) {
      src = w_in; dst = wt_in; srcN = 11264; LDO = 1024;
      n0 = (id % 176) * 64; k0 = (id / 176) * 64; kcol0 = 0; win = true;
    } else if (id < 3072) {
      id -= 2816; src = w_attn; dst = wtcat; srcN = 1024; LDO = 5120;
      n0 = (id % 16) * 64; k0 = (id / 16) * 64; kcol0 = 0; win = false;
    } else {
      id -= 3072; src = w_ff; dst = wtcat; srcN = 1024; LDO = 5120;
      n0 = (id % 16) * 64; k0 = (id / 16) * 64; kcol0 = 1024; win = false;
    }
    int drow0;
    if (!win || n0 < 3072) {
      drow0 = n0;
    } else if (n0 < 7168) {
      int m = n0 - 3072; drow0 = 3072 + ((m >> 6) << 7);
    } else {
      int m = n0 - 7168; drow0 = 3072 + ((m >> 6) << 7) + 64;
    }
#pragma unroll
    for (int i = 0; i < 16; i++) {
      int k = i * 4 + (tid >> 6), n = tid & 63;
      t[k][n] = src[(size_t)(k0 + k) * srcN + n0 + n];
    }
    __syncthreads();
#pragma unroll
    for (int j = 0; j < 2; j++) {
      int n = j * 32 + (tid >> 3), kc = (tid & 7) * 8;
      bf16x8 o;
#pragma unroll
      for (int u = 0; u < 8; u++) o[u] = (bf16)t[kc + u][n];
      *(bf16x8*)&dst[(size_t)(drow0 + n) * LDO + kcol0 + k0 + kc] = o;
    }
  } else {
    __shared__ float rs[256], rss[256];
    const int row = blockIdx.x - 4096;
    const float* xr = x + (size_t)row * 1024;
    float4 v = *(const float4*)&xr[tid * 4];
    float s = v.x + v.y + v.z + v.w;
    float ss = v.x * v.x + v.y * v.y + v.z * v.z + v.w * v.w;
    rs[tid] = s; rss[tid] = ss;
    __syncthreads();
    for (int off = 128; off > 0; off >>= 1) {
      if (tid < off) { rs[tid] += rs[tid + off]; rss[tid] += rss[tid + off]; }
      __syncthreads();
    }
    const float mean = rs[0] * (1.f / 1024.f);
    const float var = rss[0] * (1.f / 1024.f) - mean * mean;
    const float rstd = rsqrtf(var + 1e-5f);
    const float* vp = (const float*)&v;
    for (int i = 0; i < 4; i++) {
      int c = tid * 4 + i;
      xn[(size_t)row * 1024 + c] = (bf16)((vp[i] - mean) * rstd * ln_w[c] + ln_b[c]);
    }
  }
}

// ---------------------------------------------------------------------------
// Flash attention v2 (fixed-max softmax): QBLK=128, 8 waves, 512 threads.
// Halves K/V L2/L3 traffic vs QBLK=64 (each K/V tile now reused by 8 waves,
// 16 Q-blocks per head instead of 32). Per-wave math/layout identical to
// the proven QBLK=64 version. LDS 67.6 KB -> 2 blocks/CU; grid 512 = 2/CU.
// ---------------------------------------------------------------------------
__global__ __launch_bounds__(512, 4) void flash_attn(const bf16* __restrict__ proj,
                                                     const bf16* __restrict__ vt,
                                                     bf16* __restrict__ hcat) {
  __shared__ __align__(16) char smem[67584];
  bf16* Ks = (bf16*)smem;                  // [128][64] swizzled
  bf16* Vs = (bf16*)(smem + 16384);        // [64][128] swizzled
  bf16* Ps = (bf16*)(smem + 32768);        // [8][16][136]
  const int tid = threadIdx.x;
  const int wave = tid >> 6, lane = tid & 63;
  const int quad = lane >> 4, l16 = lane & 15;
  const int q0 = blockIdx.x * 128;
  const int h = blockIdx.y, b = blockIdx.z;
  constexpr size_t LDP = 3072;
  const bf16* Qb = proj + (size_t)b * 2048 * LDP + h * 64;
  const bf16* Kb = proj + (size_t)b * 2048 * LDP + 1024 + h * 64;
  const bf16* Vt = vt + (size_t)(b * 16 + h) * 64 * 2048;

  const int qrow = q0 + wave * 16 + l16;
  bf16x8 aq0r = *(const bf16x8*)&Qb[(size_t)qrow * LDP + quad * 8];
  bf16x8 aq1r = *(const bf16x8*)&Qb[(size_t)qrow * LDP + 32 + quad * 8];
  bf16x8 aq0, aq1;
#pragma unroll
  for (int i = 0; i < 8; i++) {
    aq0[i] = (bf16)((float)aq0r[i] * 0.125f);
    aq1[i] = (bf16)((float)aq1r[i] * 0.125f);
  }

  f32x4 O[4] = {};
  float plrow[4] = {0.f, 0.f, 0.f, 0.f};  // per-lane partial row-sums

  // staging geometry (512 threads): K rows = p*64 + wave*8 + (lane>>3),
  // V rows = p*32 + wave*4 + (lane>>4); 2 loads each of K and V per thread.
  const int krow_ = wave * 8 + (lane >> 3);          // p*64 preserves &7
  const int kq_ = ((lane & 7) ^ (krow_ & 7)) * 8;    // = (lane&7)^(lane>>3)
  const int vrow_ = wave * 4 + (lane >> 4);          // p*32 preserves &15
  const int vq_ = ((lane & 15) ^ (vrow_ & 15)) * 8;

  for (int j0 = 0; j0 < 2048; j0 += 128) {
#pragma unroll
    for (int p = 0; p < 2; p++) {
      int kr = p * 64 + krow_;
      GLOBAL_LOAD_LDS16(&Kb[(size_t)(j0 + kr) * LDP + kq_],
                        &Ks[kr * 64 + (lane & 7) * 8]);
      int vr = p * 32 + vrow_;
      GLOBAL_LOAD_LDS16(&Vt[(size_t)vr * 2048 + j0 + vq_],
                        &Vs[vr * 128 + (lane & 15) * 8]);
    }
    __syncthreads();

    f32x4 sa[8];
#pragma unroll
    for (int nt = 0; nt < 8; nt++) {
      int r = nt * 16 + l16;
      bf16x8 bk0 = *(const bf16x8*)&Ks[r * 64 + (quad ^ (r & 7)) * 8];
      bf16x8 bk1 = *(const bf16x8*)&Ks[r * 64 + ((quad + 4) ^ (r & 7)) * 8];
      f32x4 t = {};
      t = MFMA16(aq0, bk0, t);
      sa[nt] = MFMA16(aq1, bk1, t);
    }

    bf16* Pw = Ps + wave * (16 * 136);
#pragma unroll
    for (int r = 0; r < 4; r++) {
      bf16* pr = &Pw[(quad * 4 + r) * 136];
      float ts = 0.f;
#pragma unroll
      for (int nt = 0; nt < 8; nt++) {
        float p = __expf(sa[nt][r]);
        pr[nt * 16 + l16] = (bf16)p;
        ts += p;
      }
      plrow[r] += ts;  // defer cross-lane reduce to epilogue
    }

#pragma unroll
    for (int kg = 0; kg < 4; kg++) {
      bf16x8 aP = *(const bf16x8*)&Pw[l16 * 136 + kg * 32 + quad * 8];
#pragma unroll
      for (int nb = 0; nb < 4; nb++) {
        int vrr = nb * 16 + l16;
        int vsl = ((kg * 4 + quad) ^ (vrr & 15)) * 8;
        bf16x8 bv = *(const bf16x8*)&Vs[vrr * 128 + vsl];
        O[nb] = MFMA16(aP, bv, O[nb]);
      }
    }
    __syncthreads();
  }

#pragma unroll
  for (int r = 0; r < 4; r++) {
    float ts = plrow[r];
#pragma unroll
    for (int d = 1; d < 16; d <<= 1) ts += __shfl_xor(ts, d, 64);
    float inv = 1.f / ts;
    size_t row = (size_t)b * 2048 + q0 + wave * 16 + quad * 4 + r;
#pragma unroll
    for (int nb = 0; nb < 4; nb++)
      hcat[row * 5120 + h * 64 + nb * 16 + l16] = (bf16)(O[nb][r] * inv);
  }
}

// ---------------------------------------------------------------------------
// proj GEMM (v4/R3-proven): 256x256, BK=32, 3-buffer LDS (96 KB),
// counted-vmcnt depth-2 pipeline, setprio around MFMA cluster.
// Epilogue split: x<8 -> Q/K -> proj; x in [8,12) -> V transposed -> vt;
// x>=12 -> ff|gate gelu -> hcat.
// ---------------------------------------------------------------------------
__global__ __launch_bounds__(512, 2) void gemm_proj(const bf16* __restrict__ A,
                                                    const bf16* __restrict__ Bt,
                                                    bf16* __restrict__ proj,
                                                    bf16* __restrict__ hcat,
                                                    bf16* __restrict__ vt) {
  constexpr int K = 1024, NT = 32;
  __shared__ __align__(16) char smem[98304];   // 3 x (As 16K + Bs 16K)
  const int tid = threadIdx.x;
  const int wave = tid >> 6, lane = tid & 63;
  const int quad = lane >> 4, l16 = lane & 15;
  const int wm0 = (wave >> 2) * 128, wn0 = (wave & 3) * 64;
  const size_t rowA0 = (size_t)blockIdx.y * 256;
  const size_t rowB0 = (size_t)blockIdx.x * 256;
  const bf16* Ag = A + rowA0 * K;
  const bf16* Bg = Bt + rowB0 * K;

  const int srow = tid >> 2;
  const int sslot = tid & 3;
  const int rslot = (quad ^ ((l16 >> 1) & 3)) * 8;

  f32x4 acc[8][4] = {};

  auto STAGE = [&](int kt, int buf) {
    bf16* As = (bf16*)(smem + buf * 32768);
    bf16* Bs = As + 256 * 32;
    const int k0 = kt * 32;
#pragma unroll
    for (int p = 0; p < 2; p++) {
      int r = p * 128 + srow;
      int kq = (sslot ^ ((r >> 1) & 3)) * 8;
      GLOBAL_LOAD_LDS16(&Ag[(size_t)r * K + k0 + kq], &As[r * 32 + sslot * 8]);
      GLOBAL_LOAD_LDS16(&Bg[(size_t)r * K + k0 + kq], &Bs[r * 32 + sslot * 8]);
    }
  };

  STAGE(0, 0);
  STAGE(1, 1);
  asm volatile("s_waitcnt vmcnt(4)" ::: "memory");  // kt0 landed, kt1 in flight
  __builtin_amdgcn_s_barrier();
  asm volatile("" ::: "memory");

  int cbuf = 0, sbuf = 2;
#pragma unroll 1
  for (int kt = 0; kt < NT; kt++) {
    if (kt + 2 < NT) STAGE(kt + 2, sbuf);
    const bf16* As = (const bf16*)(smem + cbuf * 32768);
    const bf16* Bs = As + 256 * 32;
    bf16x8 bfr[4];
#pragma unroll
    for (int j = 0; j < 4; j++)
      bfr[j] = *(const bf16x8*)&Bs[(wn0 + j * 16 + l16) * 32 + rslot];
#pragma unroll
    for (int ih = 0; ih < 2; ih++) {
      bf16x8 af[4];
#pragma unroll
      for (int i = 0; i < 4; i++)
        af[i] = *(const bf16x8*)&As[(wm0 + (ih * 4 + i) * 16 + l16) * 32 + rslot];
      __builtin_amdgcn_s_setprio(1);
#pragma unroll
      for (int i = 0; i < 4; i++)
#pragma unroll
        for (int j = 0; j < 4; j++)
          acc[ih * 4 + i][j] = MFMA16(af[i], bfr[j], acc[ih * 4 + i][j]);
      __builtin_amdgcn_s_setprio(0);
    }
    if (kt + 2 < NT) {
      asm volatile("s_waitcnt vmcnt(4)" ::: "memory");  // kt+1 landed
    } else {
      asm volatile("s_waitcnt vmcnt(0)" ::: "memory");  // tail drain
    }
    __builtin_amdgcn_s_barrier();
    asm volatile("" ::: "memory");
    cbuf = (cbuf == 2) ? 0 : cbuf + 1;
    sbuf = (sbuf == 2) ? 0 : sbuf + 1;
  }

  // epilogue: two 128-row halves through LDS
  {
    const int xb = (int)blockIdx.x;
    const int T2 = xb - 12;
    bf16* Cs = (bf16*)smem;          // [128][264]
    constexpr int LDC2 = 264;
#pragma unroll 1
    for (int h = 0; h < 2; h++) {
      if ((wave >> 2) == h) {
#pragma unroll
        for (int i = 0; i < 8; i++)
#pragma unroll
          for (int j = 0; j < 4; j++)
#pragma unroll
            for (int r = 0; r < 4; r++)
              Cs[(i * 16 + quad * 4 + r) * LDC2 + wn0 + j * 16 + l16] =
                  (bf16)acc[i][j][r];
      }
      __syncthreads();
      if (xb < 8) {
        // Q/K tiles -> proj
#pragma unroll
        for (int it = 0; it < 8; it++) {
          int idx = it * 512 + tid;          // 128 rows x 32 chunks
          int row = idx >> 5, ch = (idx & 31) * 8;
          *(bf16x8*)&proj[(rowA0 + h * 128 + row) * 3072 + rowB0 + ch] =
              *(const bf16x8*)&Cs[row * LDC2 + ch];
        }
      } else if (T2 < 0) {
        // V tiles -> vt transposed: vt[(b*16+head)*64+d][s]
        const int g0 = (int)rowA0 + h * 128;   // global row base (b*2048+s)
        const int bb = g0 >> 11, sloc0 = g0 & 2047;
        const int hb = (xb - 8) * 4;           // head base for this tile
        bf16* vtb = vt + ((size_t)(bb * 16 + hb) * 64) * 2048 + sloc0;
#pragma unroll
        for (int it = 0; it < 8; it++) {
          int u = it * 512 + tid;              // 4096 units
          int col = u & 255, sc = u >> 8;      // col = head*64+d, sc = s-chunk
          bf16x8 o;
#pragma unroll
          for (int k = 0; k < 8; k++) o[k] = Cs[(sc * 8 + k) * LDC2 + col];
          *(bf16x8*)&vtb[(size_t)col * 2048 + sc * 8] = o;
        }
      } else {
        // ff|gate gelu -> hcat
#pragma unroll
        for (int it = 0; it < 4; it++) {
          int idx = it * 512 + tid;          // 128 rows x 2 pairs x 8 chunks
          int row = idx >> 4;
          int p = (idx >> 3) & 1, c8 = (idx & 7) * 8;
          bf16x8 f = *(const bf16x8*)&Cs[row * LDC2 + p * 128 + c8];
          bf16x8 g = *(const bf16x8*)&Cs[row * LDC2 + p * 128 + 64 + c8];
          bf16x8 o;
#pragma unroll
          for (int i = 0; i < 8; i++) {
            float xg = (float)g[i];
            float u = 0.7978845608f * (xg + 0.044715f * xg * xg * xg);
            float gl = xg / (1.f + __expf(-2.f * u));
            o[i] = (bf16)((float)f[i] * gl);
          }
          *(bf16x8*)&hcat[(rowA0 + h * 128 + row) * 5120 + 1024 +
                          (2 * T2 + p) * 64 + c8] = o;
        }
      }
      __syncthreads();
    }
  }
}

// ---------------------------------------------------------------------------
// Output GEMM v2 (R5-proven): 256x256 tile, BK=32, 3-buffer counted-vmcnt,
// 8 waves, split-K=4 -> grid dim3(4,16,4) = 256 blocks = 1/CU, zero tail.
// ---------------------------------------------------------------------------
__global__ __launch_bounds__(512, 2) void gemm_out(const bf16* __restrict__ A,
                                                   const bf16* __restrict__ Bt,
                                                   bf16* __restrict__ part) {
  constexpr int LDAB = 5120, NT = 40;
  __shared__ __align__(16) char smem[98304];   // 3 x (As 16K + Bs 16K)
  const int tid = threadIdx.x;
  const int wave = tid >> 6, lane = tid & 63;
  const int quad = lane >> 4, l16 = lane & 15;
  const int wm0 = (wave >> 2) * 128, wn0 = (wave & 3) * 64;
  const size_t rowA0 = (size_t)blockIdx.y * 256;
  const size_t rowB0 = (size_t)blockIdx.x * 256;
  const int kbeg = blockIdx.z * 1280;
  const bf16* Ag = A + rowA0 * LDAB + kbeg;
  const bf16* Bg = Bt + rowB0 * LDAB + kbeg;

  const int srow = tid >> 2;
  const int sslot = tid & 3;
  const int rslot = (quad ^ ((l16 >> 1) & 3)) * 8;

  f32x4 acc[8][4] = {};

  auto STAGE = [&](int kt, int buf) {
    bf16* As = (bf16*)(smem + buf * 32768);
    bf16* Bs = As + 256 * 32;
    const int k0 = kt * 32;
#pragma unroll
    for (int p = 0; p < 2; p++) {
      int r = p * 128 + srow;
      int kq = (sslot ^ ((r >> 1) & 3)) * 8;
      GLOBAL_LOAD_LDS16(&Ag[(size_t)r * LDAB + k0 + kq], &As[r * 32 + sslot * 8]);
      GLOBAL_LOAD_LDS16(&Bg[(size_t)r * LDAB + k0 + kq], &Bs[r * 32 + sslot * 8]);
    }
  };

  STAGE(0, 0);
  STAGE(1, 1);
  asm volatile("s_waitcnt vmcnt(4)" ::: "memory");
  __builtin_amdgcn_s_barrier();
  asm volatile("" ::: "memory");

  int cbuf = 0, sbuf = 2;
#pragma unroll 1
  for (int kt = 0; kt < NT; kt++) {
    if (kt + 2 < NT) STAGE(kt + 2, sbuf);
    const bf16* As = (const bf16*)(smem + cbuf * 32768);
    const bf16* Bs = As + 256 * 32;
    bf16x8 bfr[4];
#pragma unroll
    for (int j = 0; j < 4; j++)
      bfr[j] = *(const bf16x8*)&Bs[(wn0 + j * 16 + l16) * 32 + rslot];
#pragma unroll
    for (int ih = 0; ih < 2; ih++) {
      bf16x8 af[4];
#pragma unroll
      for (int i = 0; i < 4; i++)
        af[i] = *(const bf16x8*)&As[(wm0 + (ih * 4 + i) * 16 + l16) * 32 + rslot];
      __builtin_amdgcn_s_setprio(1);
#pragma unroll
      for (int i = 0; i < 4; i++)
#pragma unroll
        for (int j = 0; j < 4; j++)
          acc[ih * 4 + i][j] = MFMA16(af[i], bfr[j], acc[ih * 4 + i][j]);
      __builtin_amdgcn_s_setprio(0);
    }
    if (kt + 2 < NT) {
      asm volatile("s_waitcnt vmcnt(4)" ::: "memory");
    } else {
      asm volatile("s_waitcnt vmcnt(0)" ::: "memory");
    }
    __builtin_amdgcn_s_barrier();
    asm volatile("" ::: "memory");
    cbuf = (cbuf == 2) ? 0 : cbuf + 1;
    sbuf = (sbuf == 2) ? 0 : sbuf + 1;
  }

  // epilogue: two 128-row halves through LDS -> part[z]
  {
    bf16* dst = part + (size_t)blockIdx.z * (4096 * 1024);
    bf16* Cs = (bf16*)smem;          // [128][264]
    constexpr int LDC2 = 264;
#pragma unroll 1
    for (int h = 0; h < 2; h++) {
      if ((wave >> 2) == h) {
#pragma unroll
        for (int i = 0; i < 8; i++)
#pragma unroll
          for (int j = 0; j < 4; j++)
#pragma unroll
            for (int r = 0; r < 4; r++)
              Cs[(i * 16 + quad * 4 + r) * LDC2 + wn0 + j * 16 + l16] =
                  (bf16)acc[i][j][r];
      }
      __syncthreads();
#pragma unroll
      for (int it = 0; it < 8; it++) {
        int idx = it * 512 + tid;          // 128 rows x 32 chunks
        int row = idx >> 5, ch = (idx & 31) * 8;
        *(bf16x8*)&dst[(rowA0 + h * 128 + row) * 1024 + rowB0 + ch] =
            *(const bf16x8*)&Cs[row * LDC2 + ch];
      }
      __syncthreads();
    }
  }
}

// ---------------------------------------------------------------------------
// out = x + sum of 4 bf16 partials
// ---------------------------------------------------------------------------
__global__ __launch_bounds__(256) void reduce_out(const float* __restrict__ x,
                                                  const bf16* __restrict__ part,
                                                  float* __restrict__ out) {
  const size_t i = ((size_t)blockIdx.x * 256 + threadIdx.x) * 8;
  constexpr size_t SL = 4096 * 1024;
  float r[8];
  float4 x0 = *(const float4*)&x[i];
  float4 x1 = *(const float4*)&x[i + 4];
  r[0] = x0.x; r[1] = x0.y; r[2] = x0.z; r[3] = x0.w;
  r[4] = x1.x; r[5] = x1.y; r[6] = x1.z; r[7] = x1.w;
#pragma unroll
  for (int z = 0; z < 4; z++) {
    bf16x8 p = *(const bf16x8*)&part[z * SL + i];
#pragma unroll
    for (int k = 0; k < 8; k++) r[k] += (float)p[k];
  }
  float4 o0 = {r[0], r[1], r[2], r[3]};
  float4 o1 = {r[4], r[5], r[6], r[7]};
  *(float4*)&out[i] = o0;
  *(float4*)&out[i + 4] = o1;
}

// ---------------------------------------------------------------------------
extern "C" void kernel_launch(void* const* d_in, const int* in_sizes, int n_in,
                              void* d_out, int out_size, void* d_ws, size_t ws_size,
                              hipStream_t stream) {
  const float* x      = (const float*)d_in[0];
  const float* ln_w   = (const float*)d_in[1];
  const float* ln_b   = (const float*)d_in[2];
  const float* w_in   = (const float*)d_in[3];  // [1024,11264]
  const float* w_attn = (const float*)d_in[4];  // [1024,1024]
  const float* w_ff   = (const float*)d_in[5];  // [4096,1024]
  float* out = (float*)d_out;
  char* ws = (char*)d_ws;

  bf16* wt_in = (bf16*)(ws);                 // [11264][1024] 23068672 B
  bf16* wtcat = (bf16*)(ws + 23068672);      // [1024][5120]  10485760 B
  bf16* xn    = (bf16*)(ws + 33554432);      // [4096][1024]   8388608 B
  bf16* proj  = (bf16*)(ws + 41943040);      // [4096][3072]  25165824 B
  bf16* part  = (bf16*)(ws + 67108864);      // 4x[4096][1024] 33554432 B
  bf16* vt    = (bf16*)(ws + 100663296);     // [32][64][2048]  8388608 B
  bf16* hcat  = (bf16*)(ws + 134217728);     // [4096][5120]  41943040 B

  prep<<<8192, 256, 0, stream>>>(w_in, w_attn, w_ff, wt_in, wtcat,
                                 x, ln_w, ln_b, xn);
  gemm_proj<<<dim3(44, 16), 512, 0, stream>>>(xn, wt_in, proj, hcat, vt);
  flash_attn<<<dim3(16, 16, 2), 512, 0, stream>>>(proj, vt, hcat);
  gemm_out<<<dim3(4, 16, 4), 512, 0, stream>>>(hcat, wtcat, part);
  reduce_out<<<2048, 256, 0, stream>>>(x, part, out);
}